// Round 15
// baseline (343.284 us; speedup 1.0000x reference)
//
#include <hip/hip_runtime.h>

constexpr int Bc = 4, Hc = 8, Nc = 2048, Dc = 64, Fc = 128, Mc = 4;
constexpr int BHc = Bc*Hc;        // 32
constexpr int T2c = 2*Nc;         // 4096
constexpr int Jc  = Mc*Fc;        // 512
constexpr float DNORM = 0.4204482076268573f;   // 32^-0.25

// workspace offsets (in floats)
constexpr size_t OFF_AS    = 0;                                 // 16777216 (AS; also AS_S scratch pre-fuse)
constexpr size_t OFF_XSH   = OFF_AS    + (size_t)BHc*T2c*Fc;    // xs h-plane (ushort)
constexpr size_t OFF_XSM   = OFF_XSH   + (size_t)BHc*Jc*Dc/2;
constexpr size_t OFF_XSL   = OFF_XSM   + (size_t)BHc*Jc*Dc/2;
constexpr size_t OFF_DIAG1 = OFF_XSL   + (size_t)BHc*Jc*Dc/2;
constexpr size_t OFF_DIAG2 = OFF_DIAG1 + (size_t)BHc*T2c;
constexpr size_t OFF_STASN = OFF_DIAG2 + (size_t)BHc*Jc;
constexpr size_t OFF_VBUF  = OFF_STASN + (size_t)BHc*Fc*Fc;
constexpr size_t OFF_DINV  = OFF_VBUF  + (size_t)BHc*Fc*Fc;
constexpr size_t OFF_GMAX  = OFF_DINV  + (size_t)BHc*Fc;
constexpr size_t OFF_CTX   = OFF_GMAX  + 64;
constexpr size_t OFF_KH    = OFF_CTX   + (size_t)BHc*Fc*Dc;     // K h-plane (ushort)
constexpr size_t OFF_KM    = OFF_KH    + (size_t)BHc*Fc*Fc/2;
constexpr size_t OFF_KL    = OFF_KM    + (size_t)BHc*Fc*Fc/2;
constexpr size_t OFF_ZSC   = OFF_KL    + (size_t)BHc*Fc*Fc/2;   // Zl scratch (fresh: xs planes live during fuse)
// GPART reuses xs-plane region (dead after fused kernel):
constexpr size_t OFF_GPART = OFF_XSH;                           // [BHc][4][128][64] floats
// AS_S scratch: first 2M floats of AS region (consumed by stas before AS is written)
constexpr size_t OFF_ASS   = OFF_AS;

typedef __attribute__((ext_vector_type(8))) short bf16x8;
typedef __attribute__((ext_vector_type(4))) float f32x4;
typedef __attribute__((ext_vector_type(4))) unsigned short u16x4;

__device__ __forceinline__ unsigned short f2bf_rne(float x) {
  unsigned int u = __float_as_uint(x);
  u += 0x7fff + ((u >> 16) & 1);
  return (unsigned short)(u >> 16);
}
__device__ __forceinline__ float bf2f(unsigned short h) {
  return __uint_as_float(((unsigned int)h) << 16);
}

// ---------------- diag1 ----------------
__global__ __launch_bounds__(256) void diag1_kernel(
    const float* __restrict__ q, const float* __restrict__ k,
    const float* __restrict__ mask, float* __restrict__ diag1) {
  int gid = blockIdx.x*256 + threadIdx.x;
  int kq  = gid & 15;
  int row = gid >> 4;
  int t   = row & (T2c - 1);
  int bh  = row >> 12;
  int b   = bh >> 3;
  int tn  = (t < Nc) ? t : t - Nc;
  const float* src = ((t < Nc) ? q : k) + ((size_t)bh*Nc + tn)*Dc;
  float sc = DNORM * mask[b*Nc + tn];
  float4 x = *(const float4*)(src + kq*4);
  float s = x.x*x.x + x.y*x.y + x.z*x.z + x.w*x.w;
  s += __shfl_xor(s, 1);
  s += __shfl_xor(s, 2);
  s += __shfl_xor(s, 4);
  s += __shfl_xor(s, 8);
  if (kq == 0) diag1[row] = 0.5f * sc * sc * s;
}

// ---------------- gather -> pre-split bf16 h/m/l planes + diag2 ----------------
__global__ __launch_bounds__(256) void gather_kernel(
    const float* __restrict__ q, const float* __restrict__ k,
    const float* __restrict__ mask, const int* __restrict__ sketch,
    const float* __restrict__ diag1,
    unsigned short* __restrict__ xsh, unsigned short* __restrict__ xsm,
    unsigned short* __restrict__ xsl, float* __restrict__ diag2) {
  int gid = blockIdx.x*256 + threadIdx.x;
  int kq  = gid & 15;
  int idx = gid >> 4;
  int j   = idx & (Jc - 1);
  int bh  = idx >> 9;
  int b   = bh >> 3;
  int t   = sketch[b*Jc + j];
  int tn  = (t < Nc) ? t : t - Nc;
  const float* src = ((t < Nc) ? q : k) + ((size_t)bh*Nc + tn)*Dc;
  float sc = DNORM * mask[b*Nc + tn];
  float4 x = *(const float4*)(src + kq*4);
  float xv[4] = {x.x*sc, x.y*sc, x.z*sc, x.w*sc};
  u16x4 hh, mm_, ll;
  #pragma unroll
  for (int jj = 0; jj < 4; ++jj) {
    unsigned short h = f2bf_rne(xv[jj]);
    float r1 = xv[jj] - bf2f(h);
    unsigned short m = f2bf_rne(r1);
    float r2 = r1 - bf2f(m);
    hh[jj] = h; mm_[jj] = m; ll[jj] = f2bf_rne(r2);
  }
  *(u16x4*)(xsh + (size_t)idx*Dc + kq*4) = hh;
  *(u16x4*)(xsm + (size_t)idx*Dc + kq*4) = mm_;
  *(u16x4*)(xsl + (size_t)idx*Dc + kq*4) = ll;
  if (kq == 0) diag2[idx] = diag1[bh*T2c + t];
}

// ---- swizzled [r][64]-ushort plane offset (byte) ----
__device__ __forceinline__ unsigned poff(int r, int ke) {
  unsigned byte = ((unsigned)r << 7) | ((unsigned)ke << 1);
  return byte ^ (((unsigned)(r & 7)) << 4);
}

// ---------------- shared AS-GEMM body (128 rows x 512 sketch cols), LDS-staged ----------------
// A planes already staged+split into Ah/Am/Al (swizzled). Computes 128x128 output per
// m and accumulates sign*exp(...) into oa, then writes to dst rows [row0..row0+127].
__device__ __forceinline__ void as_body(
    char* sma, const unsigned short* xhh, const unsigned short* xmm,
    const unsigned short* xll, float* __restrict__ dst, size_t dst_row_stride_base,
    int tid) {
  char* Ah = sma;
  char* Am = sma + 16384;
  char* Al = sma + 32768;
  char* Bh = sma + 49152;
  char* Bm = sma + 65536;
  char* Bl = sma + 81920;
  float* d1s = (float*)(sma + 98304);
  float* d2s = (float*)(sma + 98816);
  float* sgs = (float*)(sma + 100864);
  int lane = tid & 63, wid = tid >> 6;   // 8 waves
  int wr = wid >> 1, wc = wid & 1;
  int l16 = lane & 15, lg = lane >> 4;
  int R0 = wr*32, C0 = wc*64;

  f32x4 oa[2][4];
  #pragma unroll
  for (int m = 0; m < 2; ++m)
    #pragma unroll
    for (int n = 0; n < 4; ++n) oa[m][n] = 0.f;

  for (int m = 0; m < Mc; ++m) {
    __syncthreads();
    for (int i = tid; i < 128*16; i += 512) {
      int c = i >> 4, k4 = i & 15;
      size_t p = (size_t)(m*Fc + c)*Dc + k4*4;
      unsigned off = poff(c, k4*4);
      *(u16x4*)(Bh + off) = *(const u16x4*)(xhh + p);
      *(u16x4*)(Bm + off) = *(const u16x4*)(xmm + p);
      *(u16x4*)(Bl + off) = *(const u16x4*)(xll + p);
    }
    __syncthreads();

    f32x4 acc[2][4];
    #pragma unroll
    for (int mm = 0; mm < 2; ++mm)
      #pragma unroll
      for (int nn = 0; nn < 4; ++nn) acc[mm][nn] = 0.f;
    #pragma unroll
    for (int kc = 0; kc < Dc; kc += 32) {
      int ko = kc + lg*8;
      bf16x8 ah[2], am2[2], al2[2], bhv[4], bmv[4], blv[4];
      #pragma unroll
      for (int mm = 0; mm < 2; ++mm) {
        unsigned off = poff(R0+16*mm+l16, ko);
        ah[mm]  = *(const bf16x8*)(Ah + off);
        am2[mm] = *(const bf16x8*)(Am + off);
        al2[mm] = *(const bf16x8*)(Al + off);
      }
      #pragma unroll
      for (int nn = 0; nn < 4; ++nn) {
        unsigned off = poff(C0+16*nn+l16, ko);
        bhv[nn] = *(const bf16x8*)(Bh + off);
        bmv[nn] = *(const bf16x8*)(Bm + off);
        blv[nn] = *(const bf16x8*)(Bl + off);
      }
      #pragma unroll
      for (int mm = 0; mm < 2; ++mm)
        #pragma unroll
        for (int nn = 0; nn < 4; ++nn) {
          acc[mm][nn] = __builtin_amdgcn_mfma_f32_16x16x32_bf16(am2[mm], bmv[nn], acc[mm][nn], 0,0,0);
          acc[mm][nn] = __builtin_amdgcn_mfma_f32_16x16x32_bf16(ah[mm],  blv[nn], acc[mm][nn], 0,0,0);
          acc[mm][nn] = __builtin_amdgcn_mfma_f32_16x16x32_bf16(al2[mm], bhv[nn], acc[mm][nn], 0,0,0);
          acc[mm][nn] = __builtin_amdgcn_mfma_f32_16x16x32_bf16(ah[mm],  bmv[nn], acc[mm][nn], 0,0,0);
          acc[mm][nn] = __builtin_amdgcn_mfma_f32_16x16x32_bf16(am2[mm], bhv[nn], acc[mm][nn], 0,0,0);
          acc[mm][nn] = __builtin_amdgcn_mfma_f32_16x16x32_bf16(ah[mm],  bhv[nn], acc[mm][nn], 0,0,0);
        }
    }
    #pragma unroll
    for (int mm = 0; mm < 2; ++mm)
      #pragma unroll
      for (int nn = 0; nn < 4; ++nn) {
        int c = C0 + 16*nn + l16;
        float d2v = d2s[m*Fc + c], sg = sgs[m*Fc + c];
        #pragma unroll
        for (int r = 0; r < 4; ++r) {
          int row = R0 + 16*mm + 4*lg + r;
          oa[mm][nn][r] += sg * __expf(acc[mm][nn][r] - d1s[row] - d2v);
        }
      }
  }
  #pragma unroll
  for (int mm = 0; mm < 2; ++mm)
    #pragma unroll
    for (int nn = 0; nn < 4; ++nn) {
      int c = C0 + 16*nn + l16;
      #pragma unroll
      for (int r = 0; r < 4; ++r) {
        int row = R0 + 16*mm + 4*lg + r;
        dst[dst_row_stride_base + (size_t)row*Fc + c] = oa[mm][nn][r];
      }
    }
}

// ---------------- ass: AS at gathered rows only (512x512x64 / head) ----------------
__global__ __launch_bounds__(512) void ass_mfma_kernel(
    const unsigned short* __restrict__ xsh, const unsigned short* __restrict__ xsm,
    const unsigned short* __restrict__ xsl,
    const float* __restrict__ diag2, const float* __restrict__ sign,
    float* __restrict__ ASS) {
  extern __shared__ char sma[];
  float* d1s = (float*)(sma + 98304);
  float* d2s = (float*)(sma + 98816);
  float* sgs = (float*)(sma + 100864);
  int bh = blockIdx.y, b = bh >> 3;
  int j0 = blockIdx.x * 128;
  int tid = threadIdx.x;
  const unsigned short* xhh = xsh + (size_t)bh*Jc*Dc;
  const unsigned short* xmm = xsm + (size_t)bh*Jc*Dc;
  const unsigned short* xll = xsl + (size_t)bh*Jc*Dc;

  // stage A tile from pre-split xs planes (rows j0..j0+127)
  for (int i = tid; i < 128*16; i += 512) {
    int r = i >> 4, kq = i & 15;
    size_t p = (size_t)(j0 + r)*Dc + kq*4;
    unsigned off = poff(r, kq*4);
    *(u16x4*)(sma + off)         = *(const u16x4*)(xhh + p);
    *(u16x4*)(sma + 16384 + off) = *(const u16x4*)(xmm + p);
    *(u16x4*)(sma + 32768 + off) = *(const u16x4*)(xll + p);
  }
  if (tid < 128) d1s[tid] = diag2[bh*Jc + j0 + tid];
  for (int i = tid; i < 512; i += 512) {
    d2s[i] = diag2[bh*Jc + i];
    sgs[i] = sign[b*Jc + i];
  }
  as_body(sma, xhh, xmm, xll, ASS, (size_t)bh*Jc*Fc + (size_t)j0*Fc, tid);
}

// ---------------- STAS build (dense AS_S reads) + normalize + K planes + gmax ----------------
__global__ __launch_bounds__(256) void stas_kernel(
    const float* __restrict__ ASS, const float* __restrict__ sign,
    float* __restrict__ STASn, float* __restrict__ Dinv,
    unsigned short* __restrict__ Kh, unsigned short* __restrict__ Km,
    unsigned short* __restrict__ Kl,
    unsigned int* __restrict__ gmax) {
  extern __shared__ float stas[];   // [128][129]
  __shared__ float sgn[Jc];
  __shared__ float Dl[Fc];
  __shared__ float red[Fc];
  int bh = blockIdx.x;
  int b  = bh >> 3;
  int tid = threadIdx.x;
  for (int i = tid; i < Jc; i += 256) sgn[i] = sign[b*Jc + i];
  __syncthreads();
  for (int i = tid; i < Fc*Fc; i += 256) {
    int dd = i >> 7, e = i & 127;
    float vsum = 0.f;
    #pragma unroll
    for (int m = 0; m < Mc; ++m)
      vsum += sgn[m*Fc + dd] * ASS[((size_t)bh*Jc + m*Fc + dd)*Fc + e];
    if (dd == e) vsum += 0.1f;
    stas[dd*129 + e] = vsum;
  }
  __syncthreads();
  if (tid < Fc) {
    float s = 0.f;
    for (int e = 0; e < Fc; ++e) s += stas[tid*129 + e];
    float di = 1.0f / sqrtf(s);
    Dl[tid] = di;
    Dinv[bh*Fc + tid] = di;
  }
  __syncthreads();
  for (int i = tid; i < Fc*Fc; i += 256) {
    int dd = i >> 7, e = i & 127;
    float vv = stas[dd*129 + e] * Dl[dd] * Dl[e];
    stas[dd*129 + e] = vv;
    STASn[(size_t)bh*Fc*Fc + i] = vv;
    unsigned short hb = f2bf_rne(vv); float r1 = vv - bf2f(hb);
    unsigned short mb = f2bf_rne(r1); float r2 = r1 - bf2f(mb);
    Kh[(size_t)bh*Fc*Fc + i] = hb;
    Km[(size_t)bh*Fc*Fc + i] = mb;
    Kl[(size_t)bh*Fc*Fc + i] = f2bf_rne(r2);
  }
  __syncthreads();
  if (tid < Fc) {
    float s = 0.f;
    for (int dd = 0; dd < Fc; ++dd) s += stas[dd*129 + tid];
    red[tid] = s;
  }
  __syncthreads();
  if (tid == 0) {
    float mx = 0.f;
    for (int e = 0; e < Fc; ++e) mx = fmaxf(mx, red[e]);
    atomicMax(gmax, __float_as_uint(mx));
  }
}

// ---------------- Newton helpers (round-8 body) ----------------
__device__ __forceinline__ unsigned boff(int brow, int ke) {
  unsigned byte = ((unsigned)brow << 8) | ((unsigned)ke << 1);
  return byte ^ (((unsigned)(brow & 7)) << 4);
}

__device__ __forceinline__ void mm6(const bf16x8 ah[2], const bf16x8 am[2], const bf16x8 al[2],
                                    const bf16x8 bh[4], const bf16x8 bm[4], const bf16x8 bl[4],
                                    f32x4 acc[2][4]) {
  #pragma unroll
  for (int m = 0; m < 2; ++m)
    #pragma unroll
    for (int n = 0; n < 4; ++n) {
      acc[m][n] = __builtin_amdgcn_mfma_f32_16x16x32_bf16(am[m], bm[n], acc[m][n], 0,0,0);
      acc[m][n] = __builtin_amdgcn_mfma_f32_16x16x32_bf16(ah[m], bl[n], acc[m][n], 0,0,0);
      acc[m][n] = __builtin_amdgcn_mfma_f32_16x16x32_bf16(al[m], bh[n], acc[m][n], 0,0,0);
      acc[m][n] = __builtin_amdgcn_mfma_f32_16x16x32_bf16(ah[m], bm[n], acc[m][n], 0,0,0);
      acc[m][n] = __builtin_amdgcn_mfma_f32_16x16x32_bf16(am[m], bh[n], acc[m][n], 0,0,0);
      acc[m][n] = __builtin_amdgcn_mfma_f32_16x16x32_bf16(ah[m], bh[n], acc[m][n], 0,0,0);
    }
}

__device__ __forceinline__ void ld3(const char* Ph, const char* Pm, const char* Pl,
                                    int brow, int ko, bf16x8& h, bf16x8& m, bf16x8& l) {
  unsigned off = boff(brow, ko);
  h = *(const bf16x8*)(Ph + off);
  m = *(const bf16x8*)(Pm + off);
  l = *(const bf16x8*)(Pl + off);
}

__device__ __forceinline__ void mm_p1(
    const unsigned short* __restrict__ kh, const unsigned short* __restrict__ km,
    const unsigned short* __restrict__ kl,
    const char* Ah, const char* Am, const char* Al,
    int R0, int C0, int l16, int lg, f32x4 acc[2][4]) {
  #pragma unroll 2
  for (int kc = 0; kc < Fc; kc += 32) {
    int ko = kc + lg*8;
    bf16x8 ah[2], am[2], al[2], bh[4], bm[4], bl[4];
    #pragma unroll
    for (int m = 0; m < 2; ++m) {
      size_t p = (size_t)(R0+16*m+l16)*Fc + ko;
      ah[m] = *(const bf16x8*)(kh + p);
      am[m] = *(const bf16x8*)(km + p);
      al[m] = *(const bf16x8*)(kl + p);
    }
    #pragma unroll
    for (int n = 0; n < 4; ++n)
      ld3(Ah, Am, Al, C0+16*n+l16, ko, bh[n], bm[n], bl[n]);
    mm6(ah, am, al, bh, bm, bl, acc);
  }
}

__device__ __forceinline__ void mm_p234(
    const char* Ah, const char* Am, const char* Al,
    const char* Zh, const char* Zm, const unsigned short* __restrict__ ZlG,
    int R0, int C0, int l16, int lg, f32x4 acc[2][4]) {
  #pragma unroll 1
  for (int kc = 0; kc < Fc; kc += 32) {
    int ko = kc + lg*8;
    bf16x8 ah[2], am[2], al[2], bh[4], bm[4], bl[4];
    #pragma unroll
    for (int m = 0; m < 2; ++m)
      ld3(Ah, Am, Al, R0+16*m+l16, ko, ah[m], am[m], al[m]);
    #pragma unroll
    for (int n = 0; n < 4; ++n) {
      int col = C0+16*n+l16;
      unsigned off = boff(col, ko);
      bh[n] = *(const bf16x8*)(Zh + off);
      bm[n] = *(const bf16x8*)(Zm + off);
      bl[n] = *(const bf16x8*)(ZlG + col*Fc + ko);
    }
    mm6(ah, am, al, bh, bm, bl, acc);
  }
}

__device__ __forceinline__ void split4(f32x4 v, u16x4& hv, u16x4& mv, u16x4& lv) {
  #pragma unroll
  for (int r = 0; r < 4; ++r) {
    unsigned short hb = f2bf_rne(v[r]); float r1 = v[r] - bf2f(hb);
    unsigned short mb = f2bf_rne(r1);   float r2 = r1 - bf2f(mb);
    hv[r] = hb; mv[r] = mb; lv[r] = f2bf_rne(r2);
  }
}
__device__ __forceinline__ void wbA3(char* Ah, char* Am, char* Al,
                                     int col, int row0, f32x4 v) {
  u16x4 hv, mv, lv;
  split4(v, hv, mv, lv);
  unsigned off = boff(col, row0);
  *(u16x4*)(Ah + off) = hv;
  *(u16x4*)(Am + off) = mv;
  *(u16x4*)(Al + off) = lv;
}
__device__ __forceinline__ void wbZ3(char* Zh, char* Zm, unsigned short* __restrict__ ZlG,
                                     int col, int row0, f32x4 v) {
  u16x4 hv, mv, lv;
  split4(v, hv, mv, lv);
  unsigned off = boff(col, row0);
  *(u16x4*)(Zh + off) = hv;
  *(u16x4*)(Zm + off) = mv;
  *(u16x4*)(ZlG + col*Fc + row0) = lv;
}

// ---------------- fused: newton (blocks 0..31) + as_mfma (blocks 32..1055) ----------------
__global__ __launch_bounds__(512) void newton_as_kernel(
    const float* __restrict__ STASn,
    const unsigned short* __restrict__ KhG, const unsigned short* __restrict__ KmG,
    const unsigned short* __restrict__ KlG,
    const float* __restrict__ gmaxf, float* __restrict__ Vout,
    unsigned short* __restrict__ ZlScr,
    const float* __restrict__ q, const float* __restrict__ k,
    const float* __restrict__ mask,
    const unsigned short* __restrict__ xsh, const unsigned short* __restrict__ xsm,
    const unsigned short* __restrict__ xsl,
    const float* __restrict__ diag1, const float* __restrict__ diag2,
    const float* __restrict__ sign, float* __restrict__ AS) {
  extern __shared__ char smc[];
  int tid  = threadIdx.x;

  if (blockIdx.x < BHc) {
    // ================= Newton path (round-8 body) =================
    char* Ah = smc;
    char* Am = smc + 32768;
    char* Al = smc + 65536;
    char* Zh = smc + 98304;
    char* Zm = smc + 131072;
    int bh = blockIdx.x;
    const float* Kp = STASn + (size_t)bh*Fc*Fc;
    const unsigned short* kh = KhG + (size_t)bh*Fc*Fc;
    const unsigned short* km = KmG + (size_t)bh*Fc*Fc;
    const unsigned short* kl = KlG + (size_t)bh*Fc*Fc;
    unsigned short* ZlG = ZlScr + (size_t)bh*Fc*Fc;
    float ginv = 1.0f / gmaxf[0];
    int lane = tid & 63;
    int wid  = tid >> 6;
    int wr = wid >> 1, wc = wid & 1;
    int l16 = lane & 15, lg = lane >> 4;
    int R0 = wr*32, C0 = wc*64;
    int drow0 = lg*4;

    f32x4 vreg[2][4];
    #pragma unroll
    for (int m = 0; m < 2; ++m)
      #pragma unroll
      for (int n = 0; n < 4; ++n) {
        int col = C0 + 16*n + l16;
        #pragma unroll
        for (int r = 0; r < 4; ++r)
          vreg[m][n][r] = Kp[(size_t)(R0 + 16*m + drow0 + r)*Fc + col] * ginv;
        wbA3(Ah, Am, Al, col, R0 + 16*m + drow0, vreg[m][n]);
      }
    __syncthreads();

    f32x4 fin[2][4];
    for (int it = 0; it < 6; ++it) {
      f32x4 acc[2][4];
      // P1: Z = K @ V
      #pragma unroll
      for (int m = 0; m < 2; ++m) for (int n = 0; n < 4; ++n) acc[m][n] = 0.f;
      mm_p1(kh, km, kl, Ah, Am, Al, R0, C0, l16, lg, acc);
      #pragma unroll
      for (int m = 0; m < 2; ++m)
        #pragma unroll
        for (int n = 0; n < 4; ++n)
          wbZ3(Zh, Zm, ZlG, C0 + 16*n + l16, R0 + 16*m + drow0, acc[m][n]);
      __syncthreads();

      // P2: W1 = V @ Z ; fin = 13V - 15W1
      #pragma unroll
      for (int m = 0; m < 2; ++m) for (int n = 0; n < 4; ++n) acc[m][n] = 0.f;
      mm_p234(Ah, Am, Al, Zh, Zm, ZlG, R0, C0, l16, lg, acc);
      #pragma unroll
      for (int m = 0; m < 2; ++m)
        #pragma unroll
        for (int n = 0; n < 4; ++n)
          fin[m][n] = 13.f*vreg[m][n] - 15.f*acc[m][n];
      __syncthreads();
      #pragma unroll
      for (int m = 0; m < 2; ++m)
        #pragma unroll
        for (int n = 0; n < 4; ++n)
          wbA3(Ah, Am, Al, C0 + 16*n + l16, R0 + 16*m + drow0, acc[m][n]);
      __syncthreads();

      // P3: W2 = W1 @ Z ; fin += 7W2
      #pragma unroll
      for (int m = 0; m < 2; ++m) for (int n = 0; n < 4; ++n) acc[m][n] = 0.f;
      mm_p234(Ah, Am, Al, Zh, Zm, ZlG, R0, C0, l16, lg, acc);
      #pragma unroll
      for (int m = 0; m < 2; ++m)
        #pragma unroll
        for (int n = 0; n < 4; ++n)
          fin[m][n] += 7.f*acc[m][n];
      __syncthreads();
      #pragma unroll
      for (int m = 0; m < 2; ++m)
        #pragma unroll
        for (int n = 0; n < 4; ++n)
          wbA3(Ah, Am, Al, C0 + 16*n + l16, R0 + 16*m + drow0, acc[m][n]);
      __syncthreads();

      // P4: W3 = W2 @ Z ; V <- 0.25(fin - W3)
      #pragma unroll
      for (int m = 0; m < 2; ++m) for (int n = 0; n < 4; ++n) acc[m][n] = 0.f;
      mm_p234(Ah, Am, Al, Zh, Zm, ZlG, R0, C0, l16, lg, acc);
      #pragma unroll
      for (int m = 0; m < 2; ++m)
        #pragma unroll
        for (int n = 0; n < 4; ++n) {
          fin[m][n] = 0.25f*(fin[m][n] - acc[m][n]);
          vreg[m][n] = fin[m][n];
        }
      __syncthreads();
      #pragma unroll
      for (int m = 0; m < 2; ++m)
        #pragma unroll
        for (int n = 0; n < 4; ++n)
          wbA3(Ah, Am, Al, C0 + 16*n + l16, R0 + 16*m + drow0, fin[m][n]);
      __syncthreads();
    }

    float* Vo = Vout + (size_t)bh*Fc*Fc;
    #pragma unroll
    for (int m = 0; m < 2; ++m)
      #pragma unroll
      for (int n = 0; n < 4; ++n) {
        int col = C0 + 16*n + l16;
        #pragma unroll
        for (int r = 0; r < 4; ++r)
          Vo[(size_t)(R0 + 16*m + drow0 + r)*Fc + col] = vreg[m][n][r];
      }
  } else {
    // ================= as_mfma path (round-14 body) =================
    int id = blockIdx.x - BHc;          // 0..1023
    int bh = id >> 5, b = bh >> 3;
    int t0 = (id & 31) * 128;
    float* d1s = (float*)(smc + 98304);
    float* d2s = (float*)(smc + 98816);
    float* sgs = (float*)(smc + 100864);

    for (int i = tid; i < 128*16; i += 512) {
      int r = i >> 4, kq = i & 15;
      int t = t0 + r;
      int tn = (t < Nc) ? t : t - Nc;
      const float* src = ((t < Nc) ? q : k) + ((size_t)bh*Nc + tn)*Dc + kq*4;
      float sc = DNORM * mask[b*Nc + tn];
      float4 x = *(const float4*)src;
      float xv[4] = {x.x*sc, x.y*sc, x.z*sc, x.w*sc};
      u16x4 hv, mv, lv;
      #pragma unroll
      for (int jj = 0; jj < 4; ++jj) {
        unsigned short h = f2bf_rne(xv[jj]);
        float r1 = xv[jj] - bf2f(h);
        unsigned short m = f2bf_rne(r1);
        float r2 = r1 - bf2f(m);
        hv[jj] = h; mv[jj] = m; lv[jj] = f2bf_rne(r2);
      }
      unsigned off = poff(r, kq*4);
      *(u16x4*)(smc + off)         = hv;
      *(u16x4*)(smc + 16384 + off) = mv;
      *(u16x4*)(smc + 32768 + off) = lv;
    }
    if (tid < 128) d1s[tid] = diag1[bh*T2c + t0 + tid];
    for (int i = tid; i < 512; i += 512) {
      d2s[i] = diag2[bh*Jc + i];
      sgs[i] = sign[b*Jc + i];
    }
    const unsigned short* xhh = xsh + (size_t)bh*Jc*Dc;
    const unsigned short* xmm = xsm + (size_t)bh*Jc*Dc;
    const unsigned short* xll = xsl + (size_t)bh*Jc*Dc;
    as_body(smc, xhh, xmm, xll, AS, (size_t)bh*T2c*Fc + (size_t)t0*Fc, tid);
  }
}

// ---------------- ctx_raw standalone: G_part = K^T (m^2 v) ----------------
__global__ __launch_bounds__(512) void ctx_raw_kernel(
    const float* __restrict__ ASg, const float* __restrict__ vg,
    const float* __restrict__ maskg, float* __restrict__ Gpart) {
  extern __shared__ char smc[];
  float* Ksh = (float*)smc;              // [64][128]
  float* vsh = (float*)(smc + 32768);    // [64][64]
  int id = blockIdx.x;                   // 0..127
  int cbh = id >> 2, chunk = id & 3;
  int cb = cbh >> 3;
  int t0 = chunk * 512;
  int tid = threadIdx.x;
  int f = tid & 127, g = tid >> 7;       // g in 0..3
  float acc[16];
  #pragma unroll
  for (int j = 0; j < 16; ++j) acc[j] = 0.f;
  for (int sub = 0; sub < 8; ++sub) {
    __syncthreads();
    int ts = t0 + sub*64;
    for (int i = tid; i < 64*32; i += 512) {
      int r = i >> 5, c4 = i & 31;
      *(float4*)&Ksh[r*128 + c4*4] =
          *(const float4*)(ASg + ((size_t)cbh*T2c + Nc + ts + r)*Fc + c4*4);
    }
    for (int i = tid; i < 64*16; i += 512) {
      int r = i >> 4, c4 = i & 15;
      float mk = maskg[cb*Nc + ts + r];
      float m2 = mk*mk;
      float4 x = *(const float4*)(vg + ((size_t)cbh*Nc + ts + r)*Dc + c4*4);
      x.x*=m2; x.y*=m2; x.z*=m2; x.w*=m2;
      *(float4*)&vsh[r*64 + c4*4] = x;
    }
    __syncthreads();
    #pragma unroll 2
    for (int tl = 0; tl < 64; ++tl) {
      float kf = Ksh[tl*128 + f];
      #pragma unroll
      for (int j4 = 0; j4 < 4; ++j4) {
        float4 vv = *(const float4*)&vsh[tl*64 + g*16 + j4*4];
        acc[j4*4+0] += kf*vv.x; acc[j4*4+1] += kf*vv.y;
        acc[j4*4+2] += kf*vv.z; acc[j4*4+3] += kf*vv.w;
      }
    }
  }
  float* gp = Gpart + ((((size_t)cbh*4 + chunk)*128 + f)*64 + g*16);
  #pragma unroll
  for (int j4 = 0; j4 < 4; ++j4)
    *(float4*)(gp + j4*4) = *(const float4*)&acc[j4*4];
}

// ---------------- ctx_fix ----------------
__global__ __launch_bounds__(256) void ctx_fix_kernel(
    const float* __restrict__ Gpart, const float* __restrict__ Vinv,
    const float* __restrict__ Dinv, float* __restrict__ ctxo) {
  __shared__ float DG[128*64];
  __shared__ float Dl[128];
  int bh = blockIdx.x;
  int tid = threadIdx.x;
  if (tid < 128) Dl[tid] = Dinv[bh*Fc + tid];
  __syncthreads();
  for (int i = tid; i < 2048; i += 256) {
    int e = i >> 4, c4 = i & 15;
    const float* g0 = Gpart + ((((size_t)bh*4)*128 + e)*64 + c4*4);
    float4 s0 = *(const float4*)(g0);
    float4 s1 = *(const float4*)(g0 + 8192);
    float4 s2 = *(const float4*)(g0 + 16384);
    float4 s3 = *(const float4*)(g0 + 24576);
    float de = Dl[e];
    float4 o;
    o.x = (s0.x+s1.x+s2.x+s3.x)*de;
    o.y = (s0.y+s1.y+s2.y+s3.y)*de;
    o.z = (s0.z+s1.z+s2.z+s3.z)*de;
    o.w = (s0.w+s1.w+s2.w+s3.w)*de;
    *(float4*)&DG[e*64 + c4*4] = o;
  }
  __syncthreads();
  int f = tid & 127, half = tid >> 7;
  float acc[32];
  #pragma unroll
  for (int j = 0; j < 32; ++j) acc[j] = 0.f;
  for (int e = 0; e < 128; ++e) {
    float s = Vinv[(size_t)bh*Fc*Fc + (size_t)e*Fc + f];
    #pragma unroll
    for (int j4 = 0; j4 < 8; ++j4) {
      float4 dg = *(const float4*)&DG[e*64 + half*32 + j4*4];
      acc[j4*4+0] += s*dg.x; acc[j4*4+1] += s*dg.y;
      acc[j4*4+2] += s*dg.z; acc[j4*4+3] += s*dg.w;
    }
  }
  float df = Dl[f];
  float* op = ctxo + (size_t)bh*Fc*Dc + f*Dc + half*32;
  #pragma unroll
  for (int j4 = 0; j4 < 8; ++j4) {
    float4 o;
    o.x = acc[j4*4+0]*df; o.y = acc[j4*4+1]*df;
    o.z = acc[j4*4+2]*df; o.w = acc[j4*4+3]*df;
    *(float4*)(op + j4*4) = o;
  }
}

// ---------------- out = Q @ context (VALU) ----------------
__global__ __launch_bounds__(256) void out_kernel(
    const float* __restrict__ AS, const float* __restrict__ ctx,
    float* __restrict__ out) {
  extern __shared__ float smo[];
  float* Asq = smo;            // [64][132]
  float* Cs  = smo + 64*132;   // [128][64]
  int bh = blockIdx.y;
  int row0 = blockIdx.x * 64;
  int tid = threadIdx.x;
  int tr = tid >> 4, tc = tid & 15;
  for (int i = tid; i < 64*32; i += 256) {
    int r = i >> 5, kq = i & 31;
    *(float4*)&Asq[r*132 + kq*4] =
        *(const float4*)(AS + ((size_t)bh*T2c + row0 + r)*Fc + kq*4);
  }
  for (int i = tid; i < 128*16; i += 256) {
    int r = i >> 4, kq = i & 15;
    *(float4*)&Cs[r*64 + kq*4] =
        *(const float4*)(ctx + (size_t)bh*Fc*Dc + r*Dc + kq*4);
  }
  __syncthreads();
  float acc[4][4] = {};
  #pragma unroll 2
  for (int kk = 0; kk < Fc; ++kk) {
    float4 bv = *(const float4*)&Cs[kk*64 + tc*4];
    float a0 = Asq[(tr*4+0)*132 + kk];
    float a1 = Asq[(tr*4+1)*132 + kk];
    float a2 = Asq[(tr*4+2)*132 + kk];
    float a3 = Asq[(tr*4+3)*132 + kk];
    acc[0][0] += a0*bv.x; acc[0][1] += a0*bv.y; acc[0][2] += a0*bv.z; acc[0][3] += a0*bv.w;
    acc[1][0] += a1*bv.x; acc[1][1] += a1*bv.y; acc[1][2] += a1*bv.z; acc[1][3] += a1*bv.w;
    acc[2][0] += a2*bv.x; acc[2][1] += a2*bv.y; acc[2][2] += a2*bv.z; acc[2][3] += a2*bv.w;
    acc[3][0] += a3*bv.x; acc[3][1] += a3*bv.y; acc[3][2] += a3*bv.z; acc[3][3] += a3*bv.w;
  }
  #pragma unroll
  for (int i = 0; i < 4; ++i) {
    float4 o;
    o.x = acc[i][0]; o.y = acc[i][1]; o.z = acc[i][2]; o.w = acc[i][3];
    *(float4*)(out + ((size_t)bh*Nc + row0 + tr*4 + i)*Dc + tc*4) = o;
  }
}

extern "C" void kernel_launch(void* const* d_in, const int* in_sizes, int n_in,
                              void* d_out, int out_size, void* d_ws, size_t ws_size,
                              hipStream_t stream) {
  const float* q    = (const float*)d_in[0];
  const float* k    = (const float*)d_in[1];
  const float* v    = (const float*)d_in[2];
  const float* mask = (const float*)d_in[3];
  const float* sign = (const float*)d_in[4];
  const int*   sketch = (const int*)d_in[5];
  float* out = (float*)d_out;
  float* ws  = (float*)d_ws;

  unsigned short* xsh = (unsigned short*)(ws + OFF_XSH);
  unsigned short* xsm = (unsigned short*)(ws + OFF_XSM);
  unsigned short* xsl = (unsigned short*)(ws + OFF_XSL);
  unsigned short* kh  = (unsigned short*)(ws + OFF_KH);
  unsigned short* km  = (unsigned short*)(ws + OFF_KM);
  unsigned short* kl  = (unsigned short*)(ws + OFF_KL);
  unsigned short* zsc = (unsigned short*)(ws + OFF_ZSC);

  hipMemsetAsync(ws + OFF_GMAX, 0, sizeof(float), stream);

  diag1_kernel<<<BHc*T2c*16/256, 256, 0, stream>>>(q, k, mask, ws + OFF_DIAG1);
  gather_kernel<<<BHc*Jc*16/256, 256, 0, stream>>>(q, k, mask, sketch, ws + OFF_DIAG1,
                                                   xsh, xsm, xsl, ws + OFF_DIAG2);
  // AS at gathered rows only (feeds stas); AS region reused as scratch pre-fuse
  ass_mfma_kernel<<<dim3(Jc/128, BHc), 512, 102912, stream>>>(xsh, xsm, xsl,
      ws + OFF_DIAG2, sign, ws + OFF_ASS);
  stas_kernel<<<BHc, 256, 128*129*sizeof(float), stream>>>(ws + OFF_ASS, sign,
      ws + OFF_STASN, ws + OFF_DINV, kh, km, kl, (unsigned int*)(ws + OFF_GMAX));
  // fused: 32 newton blocks on 32 CUs + 1024 as_mfma blocks riding the other 224 CUs
  newton_as_kernel<<<BHc + BHc*(T2c/128), 512, 163840, stream>>>(
      ws + OFF_STASN, kh, km, kl, ws + OFF_GMAX, ws + OFF_VBUF, zsc,
      q, k, mask, xsh, xsm, xsl, ws + OFF_DIAG1, ws + OFF_DIAG2, sign, ws + OFF_AS);
  ctx_raw_kernel<<<128, 512, 49152, stream>>>(ws + OFF_AS, v, mask, ws + OFF_GPART);
  ctx_fix_kernel<<<BHc, 256, 0, stream>>>(ws + OFF_GPART, ws + OFF_VBUF,
      ws + OFF_DINV, ws + OFF_CTX);
  out_kernel<<<dim3(Nc/64, BHc), 256, (64*132 + 128*64)*sizeof(float), stream>>>(
      ws + OFF_AS, ws + OFF_CTX, out);
}

// Round 16
// 323.741 us; speedup vs baseline: 1.0604x; 1.0604x over previous
//
#include <hip/hip_runtime.h>

constexpr int Bc = 4, Hc = 8, Nc = 2048, Dc = 64, Fc = 128, Mc = 4;
constexpr int BHc = Bc*Hc;        // 32
constexpr int T2c = 2*Nc;         // 4096
constexpr int Jc  = Mc*Fc;        // 512
constexpr float DNORM = 0.4204482076268573f;   // 32^-0.25

// workspace offsets (in floats)
constexpr size_t OFF_AS    = 0;                                 // 16777216
constexpr size_t OFF_XSH   = OFF_AS    + (size_t)BHc*T2c*Fc;    // xs h-plane (ushort)
constexpr size_t OFF_XSM   = OFF_XSH   + (size_t)BHc*Jc*Dc/2;
constexpr size_t OFF_XSL   = OFF_XSM   + (size_t)BHc*Jc*Dc/2;
constexpr size_t OFF_DIAG1 = OFF_XSL   + (size_t)BHc*Jc*Dc/2;
constexpr size_t OFF_DIAG2 = OFF_DIAG1 + (size_t)BHc*T2c;
constexpr size_t OFF_STASN = OFF_DIAG2 + (size_t)BHc*Jc;
constexpr size_t OFF_VBUF  = OFF_STASN + (size_t)BHc*Fc*Fc;
constexpr size_t OFF_DINV  = OFF_VBUF  + (size_t)BHc*Fc*Fc;
constexpr size_t OFF_GMAX  = OFF_DINV  + (size_t)BHc*Fc;        // gmaxv[32] floats
constexpr size_t OFF_CTX   = OFF_GMAX  + 64;
constexpr size_t OFF_KH    = OFF_CTX   + (size_t)BHc*Fc*Dc;     // K h-plane (ushort)
constexpr size_t OFF_KM    = OFF_KH    + (size_t)BHc*Fc*Fc/2;
constexpr size_t OFF_KL    = OFF_KM    + (size_t)BHc*Fc*Fc/2;
// reuse of xs-plane region (dead after as_mfma):
constexpr size_t OFF_GPART = OFF_XSH;                           // [BHc][4][128][64] floats
constexpr size_t OFF_ZSC   = OFF_GPART + (size_t)BHc*4*128*64;  // Zl scratch: BHc*16384 ushort

typedef __attribute__((ext_vector_type(8))) short bf16x8;
typedef __attribute__((ext_vector_type(4))) float f32x4;
typedef __attribute__((ext_vector_type(4))) unsigned short u16x4;

__device__ __forceinline__ unsigned short f2bf_rne(float x) {
  unsigned int u = __float_as_uint(x);
  u += 0x7fff + ((u >> 16) & 1);
  return (unsigned short)(u >> 16);
}
__device__ __forceinline__ float bf2f(unsigned short h) {
  return __uint_as_float(((unsigned int)h) << 16);
}

// ---------------- prep: diag1 (blocks 0..8191) + gather (blocks 8192..9215) ----------------
// Gather computes its diag2 locally, bit-identical to diag1[t]: same raw row
// values, same per-lane partial (x.x^2+..+x.w^2), same shfl_xor 1/2/4/8 tree,
// same 0.5*sc*sc*s final. No dependency between the two ranges.
constexpr int D1_BLOCKS = BHc*T2c*16/256;   // 8192
__global__ __launch_bounds__(256) void prep_kernel(
    const float* __restrict__ q, const float* __restrict__ k,
    const float* __restrict__ mask, const int* __restrict__ sketch,
    float* __restrict__ diag1,
    unsigned short* __restrict__ xsh, unsigned short* __restrict__ xsm,
    unsigned short* __restrict__ xsl, float* __restrict__ diag2) {
  int tid = threadIdx.x;
  if (blockIdx.x < D1_BLOCKS) {
    int gid = blockIdx.x*256 + tid;
    int kq  = gid & 15;
    int row = gid >> 4;
    int t   = row & (T2c - 1);
    int bh  = row >> 12;
    int b   = bh >> 3;
    int tn  = (t < Nc) ? t : t - Nc;
    const float* src = ((t < Nc) ? q : k) + ((size_t)bh*Nc + tn)*Dc;
    float sc = DNORM * mask[b*Nc + tn];
    float4 x = *(const float4*)(src + kq*4);
    float s = x.x*x.x + x.y*x.y + x.z*x.z + x.w*x.w;
    s += __shfl_xor(s, 1);
    s += __shfl_xor(s, 2);
    s += __shfl_xor(s, 4);
    s += __shfl_xor(s, 8);
    if (kq == 0) diag1[row] = 0.5f * sc * sc * s;
  } else {
    int gid = (blockIdx.x - D1_BLOCKS)*256 + tid;
    int kq  = gid & 15;
    int idx = gid >> 4;
    int j   = idx & (Jc - 1);
    int bh  = idx >> 9;
    int b   = bh >> 3;
    int t   = sketch[b*Jc + j];
    int tn  = (t < Nc) ? t : t - Nc;
    const float* src = ((t < Nc) ? q : k) + ((size_t)bh*Nc + tn)*Dc;
    float sc = DNORM * mask[b*Nc + tn];
    float4 x = *(const float4*)(src + kq*4);
    // diag2 = diag1[t], recomputed bit-identically from the raw row
    float s = x.x*x.x + x.y*x.y + x.z*x.z + x.w*x.w;
    s += __shfl_xor(s, 1);
    s += __shfl_xor(s, 2);
    s += __shfl_xor(s, 4);
    s += __shfl_xor(s, 8);
    float xv[4] = {x.x*sc, x.y*sc, x.z*sc, x.w*sc};
    u16x4 hh, mm_, ll;
    #pragma unroll
    for (int jj = 0; jj < 4; ++jj) {
      unsigned short h = f2bf_rne(xv[jj]);
      float r1 = xv[jj] - bf2f(h);
      unsigned short m = f2bf_rne(r1);
      float r2 = r1 - bf2f(m);
      hh[jj] = h; mm_[jj] = m; ll[jj] = f2bf_rne(r2);
    }
    *(u16x4*)(xsh + (size_t)idx*Dc + kq*4) = hh;
    *(u16x4*)(xsm + (size_t)idx*Dc + kq*4) = mm_;
    *(u16x4*)(xsl + (size_t)idx*Dc + kq*4) = ll;
    if (kq == 0) diag2[idx] = 0.5f * sc * sc * s;
  }
}

// ---- swizzled [r][64]-ushort plane offset (byte): conflict-free b128 reads ----
__device__ __forceinline__ unsigned poff(int r, int ke) {
  unsigned byte = ((unsigned)r << 7) | ((unsigned)ke << 1);
  return byte ^ (((unsigned)(r & 7)) << 4);
}

// ---------------- AS GEMM via MFMA: 128x128 tile, 8 waves, LDS-staged A&B ----------------
__global__ __launch_bounds__(512) void as_mfma_kernel(
    const float* __restrict__ q, const float* __restrict__ k,
    const float* __restrict__ mask,
    const unsigned short* __restrict__ xsh, const unsigned short* __restrict__ xsm,
    const unsigned short* __restrict__ xsl,
    const float* __restrict__ diag1, const float* __restrict__ diag2,
    const float* __restrict__ sign, float* __restrict__ AS) {
  extern __shared__ char sma[];
  char* Ah = sma;                 // [128][64] ushort, poff-swizzled (16KB each)
  char* Am = sma + 16384;
  char* Al = sma + 32768;
  char* Bh = sma + 49152;
  char* Bm = sma + 65536;
  char* Bl = sma + 81920;
  float* d1s = (float*)(sma + 98304);    // [128]
  float* d2s = (float*)(sma + 98816);    // [4][128]
  float* sgs = (float*)(sma + 100864);   // [4][128]
  int bh = blockIdx.y, b = bh >> 3;
  int t0 = blockIdx.x * 128;
  int tid = threadIdx.x;
  int lane = tid & 63, wid = tid >> 6;   // 8 waves
  int wr = wid >> 1, wc = wid & 1;
  int l16 = lane & 15, lg = lane >> 4;
  int R0 = wr*32, C0 = wc*64;

  for (int i = tid; i < 128*16; i += 512) {
    int r = i >> 4, kq = i & 15;
    int t = t0 + r;
    int tn = (t < Nc) ? t : t - Nc;
    const float* src = ((t < Nc) ? q : k) + ((size_t)bh*Nc + tn)*Dc + kq*4;
    float sc = DNORM * mask[b*Nc + tn];
    float4 x = *(const float4*)src;
    float xv[4] = {x.x*sc, x.y*sc, x.z*sc, x.w*sc};
    u16x4 hv, mv, lv;
    #pragma unroll
    for (int jj = 0; jj < 4; ++jj) {
      unsigned short h = f2bf_rne(xv[jj]);
      float r1 = xv[jj] - bf2f(h);
      unsigned short m = f2bf_rne(r1);
      float r2 = r1 - bf2f(m);
      hv[jj] = h; mv[jj] = m; lv[jj] = f2bf_rne(r2);
    }
    unsigned off = poff(r, kq*4);
    *(u16x4*)(Ah + off) = hv;
    *(u16x4*)(Am + off) = mv;
    *(u16x4*)(Al + off) = lv;
  }
  if (tid < 128) d1s[tid] = diag1[bh*T2c + t0 + tid];
  for (int i = tid; i < 512; i += 512) {
    d2s[i] = diag2[bh*Jc + i];
    sgs[i] = sign[b*Jc + i];
  }

  const unsigned short* xhh = xsh + (size_t)bh*Jc*Dc;
  const unsigned short* xmm = xsm + (size_t)bh*Jc*Dc;
  const unsigned short* xll = xsl + (size_t)bh*Jc*Dc;
  f32x4 oa[2][4];
  #pragma unroll
  for (int m = 0; m < 2; ++m)
    #pragma unroll
    for (int n = 0; n < 4; ++n) oa[m][n] = 0.f;

  for (int m = 0; m < Mc; ++m) {
    __syncthreads();
    for (int i = tid; i < 128*16; i += 512) {
      int c = i >> 4, k4 = i & 15;
      size_t p = (size_t)(m*Fc + c)*Dc + k4*4;
      unsigned off = poff(c, k4*4);
      *(u16x4*)(Bh + off) = *(const u16x4*)(xhh + p);
      *(u16x4*)(Bm + off) = *(const u16x4*)(xmm + p);
      *(u16x4*)(Bl + off) = *(const u16x4*)(xll + p);
    }
    __syncthreads();

    f32x4 acc[2][4];
    #pragma unroll
    for (int mm = 0; mm < 2; ++mm)
      #pragma unroll
      for (int nn = 0; nn < 4; ++nn) acc[mm][nn] = 0.f;
    #pragma unroll
    for (int kc = 0; kc < Dc; kc += 32) {
      int ko = kc + lg*8;
      bf16x8 ah[2], am2[2], al2[2], bhv[4], bmv[4], blv[4];
      #pragma unroll
      for (int mm = 0; mm < 2; ++mm) {
        unsigned off = poff(R0+16*mm+l16, ko);
        ah[mm]  = *(const bf16x8*)(Ah + off);
        am2[mm] = *(const bf16x8*)(Am + off);
        al2[mm] = *(const bf16x8*)(Al + off);
      }
      #pragma unroll
      for (int nn = 0; nn < 4; ++nn) {
        unsigned off = poff(C0+16*nn+l16, ko);
        bhv[nn] = *(const bf16x8*)(Bh + off);
        bmv[nn] = *(const bf16x8*)(Bm + off);
        blv[nn] = *(const bf16x8*)(Bl + off);
      }
      #pragma unroll
      for (int mm = 0; mm < 2; ++mm)
        #pragma unroll
        for (int nn = 0; nn < 4; ++nn) {
          acc[mm][nn] = __builtin_amdgcn_mfma_f32_16x16x32_bf16(am2[mm], bmv[nn], acc[mm][nn], 0,0,0);
          acc[mm][nn] = __builtin_amdgcn_mfma_f32_16x16x32_bf16(ah[mm],  blv[nn], acc[mm][nn], 0,0,0);
          acc[mm][nn] = __builtin_amdgcn_mfma_f32_16x16x32_bf16(al2[mm], bhv[nn], acc[mm][nn], 0,0,0);
          acc[mm][nn] = __builtin_amdgcn_mfma_f32_16x16x32_bf16(ah[mm],  bmv[nn], acc[mm][nn], 0,0,0);
          acc[mm][nn] = __builtin_amdgcn_mfma_f32_16x16x32_bf16(am2[mm], bhv[nn], acc[mm][nn], 0,0,0);
          acc[mm][nn] = __builtin_amdgcn_mfma_f32_16x16x32_bf16(ah[mm],  bhv[nn], acc[mm][nn], 0,0,0);
        }
    }
    #pragma unroll
    for (int mm = 0; mm < 2; ++mm)
      #pragma unroll
      for (int nn = 0; nn < 4; ++nn) {
        int c = C0 + 16*nn + l16;
        float d2v = d2s[m*Fc + c], sg = sgs[m*Fc + c];
        #pragma unroll
        for (int r = 0; r < 4; ++r) {
          int row = R0 + 16*mm + 4*lg + r;
          oa[mm][nn][r] += sg * __expf(acc[mm][nn][r] - d1s[row] - d2v);
        }
      }
  }
  #pragma unroll
  for (int mm = 0; mm < 2; ++mm)
    #pragma unroll
    for (int nn = 0; nn < 4; ++nn) {
      int c = C0 + 16*nn + l16;
      #pragma unroll
      for (int r = 0; r < 4; ++r) {
        int row = R0 + 16*mm + 4*lg + r;
        AS[((size_t)bh*T2c + t0 + row)*Fc + c] = oa[mm][nn][r];
      }
    }
}

// ---------------- STAS build + normalize + K planes + per-bh colsum max ----------------
__global__ __launch_bounds__(256) void stas_kernel(
    const float* __restrict__ AS, const int* __restrict__ sketch,
    const float* __restrict__ sign,
    float* __restrict__ STASn, float* __restrict__ Dinv,
    unsigned short* __restrict__ Kh, unsigned short* __restrict__ Km,
    unsigned short* __restrict__ Kl,
    float* __restrict__ gmaxv) {
  extern __shared__ float stas[];   // [128][129]
  __shared__ int   Ssh[Jc];
  __shared__ float sgn[Jc];
  __shared__ float Dl[Fc];
  __shared__ float red[Fc];
  int bh = blockIdx.x;
  int b  = bh >> 3;
  int tid = threadIdx.x;
  for (int i = tid; i < Jc; i += 256) {
    Ssh[i] = sketch[b*Jc + i];
    sgn[i] = sign[b*Jc + i];
  }
  __syncthreads();
  for (int i = tid; i < Fc*Fc; i += 256) {
    int dd = i >> 7, e = i & 127;
    float vsum = 0.f;
    #pragma unroll
    for (int m = 0; m < Mc; ++m) {
      int t = Ssh[m*Fc + dd];
      vsum += sgn[m*Fc + dd] * AS[((size_t)bh*T2c + t)*Fc + e];
    }
    if (dd == e) vsum += 0.1f;
    stas[dd*129 + e] = vsum;
  }
  __syncthreads();
  if (tid < Fc) {
    float s = 0.f;
    for (int e = 0; e < Fc; ++e) s += stas[tid*129 + e];
    float di = 1.0f / sqrtf(s);
    Dl[tid] = di;
    Dinv[bh*Fc + tid] = di;
  }
  __syncthreads();
  for (int i = tid; i < Fc*Fc; i += 256) {
    int dd = i >> 7, e = i & 127;
    float vv = stas[dd*129 + e] * Dl[dd] * Dl[e];
    stas[dd*129 + e] = vv;
    STASn[(size_t)bh*Fc*Fc + i] = vv;
    unsigned short hb = f2bf_rne(vv); float r1 = vv - bf2f(hb);
    unsigned short mb = f2bf_rne(r1); float r2 = r1 - bf2f(mb);
    Kh[(size_t)bh*Fc*Fc + i] = hb;
    Km[(size_t)bh*Fc*Fc + i] = mb;
    Kl[(size_t)bh*Fc*Fc + i] = f2bf_rne(r2);
  }
  __syncthreads();
  if (tid < Fc) {
    float s = 0.f;
    for (int dd = 0; dd < Fc; ++dd) s += stas[dd*129 + tid];
    red[tid] = s;
  }
  __syncthreads();
  if (tid == 0) {
    float mx = 0.f;
    for (int e = 0; e < Fc; ++e) mx = fmaxf(mx, red[e]);
    gmaxv[bh] = mx;          // plain store; newton reduces max over 32 slots
  }
}

// ---------------- Newton-Schulz (round-8 body) + fused ctx_raw ----------------
__device__ __forceinline__ unsigned boff(int brow, int ke) {
  unsigned byte = ((unsigned)brow << 8) | ((unsigned)ke << 1);
  return byte ^ (((unsigned)(brow & 7)) << 4);
}

__device__ __forceinline__ void mm6(const bf16x8 ah[2], const bf16x8 am[2], const bf16x8 al[2],
                                    const bf16x8 bh[4], const bf16x8 bm[4], const bf16x8 bl[4],
                                    f32x4 acc[2][4]) {
  #pragma unroll
  for (int m = 0; m < 2; ++m)
    #pragma unroll
    for (int n = 0; n < 4; ++n) {
      acc[m][n] = __builtin_amdgcn_mfma_f32_16x16x32_bf16(am[m], bm[n], acc[m][n], 0,0,0);
      acc[m][n] = __builtin_amdgcn_mfma_f32_16x16x32_bf16(ah[m], bl[n], acc[m][n], 0,0,0);
      acc[m][n] = __builtin_amdgcn_mfma_f32_16x16x32_bf16(al[m], bh[n], acc[m][n], 0,0,0);
      acc[m][n] = __builtin_amdgcn_mfma_f32_16x16x32_bf16(ah[m], bm[n], acc[m][n], 0,0,0);
      acc[m][n] = __builtin_amdgcn_mfma_f32_16x16x32_bf16(am[m], bh[n], acc[m][n], 0,0,0);
      acc[m][n] = __builtin_amdgcn_mfma_f32_16x16x32_bf16(ah[m], bh[n], acc[m][n], 0,0,0);
    }
}

__device__ __forceinline__ void ld3(const char* Ph, const char* Pm, const char* Pl,
                                    int brow, int ko, bf16x8& h, bf16x8& m, bf16x8& l) {
  unsigned off = boff(brow, ko);
  h = *(const bf16x8*)(Ph + off);
  m = *(const bf16x8*)(Pm + off);
  l = *(const bf16x8*)(Pl + off);
}

__device__ __forceinline__ void mm_p1(
    const unsigned short* __restrict__ kh, const unsigned short* __restrict__ km,
    const unsigned short* __restrict__ kl,
    const char* Ah, const char* Am, const char* Al,
    int R0, int C0, int l16, int lg, f32x4 acc[2][4]) {
  #pragma unroll 2
  for (int kc = 0; kc < Fc; kc += 32) {
    int ko = kc + lg*8;
    bf16x8 ah[2], am[2], al[2], bh[4], bm[4], bl[4];
    #pragma unroll
    for (int m = 0; m < 2; ++m) {
      size_t p = (size_t)(R0+16*m+l16)*Fc + ko;
      ah[m] = *(const bf16x8*)(kh + p);
      am[m] = *(const bf16x8*)(km + p);
      al[m] = *(const bf16x8*)(kl + p);
    }
    #pragma unroll
    for (int n = 0; n < 4; ++n)
      ld3(Ah, Am, Al, C0+16*n+l16, ko, bh[n], bm[n], bl[n]);
    mm6(ah, am, al, bh, bm, bl, acc);
  }
}

__device__ __forceinline__ void mm_p234(
    const char* Ah, const char* Am, const char* Al,
    const char* Zh, const char* Zm, const unsigned short* __restrict__ ZlG,
    int R0, int C0, int l16, int lg, f32x4 acc[2][4]) {
  #pragma unroll 1
  for (int kc = 0; kc < Fc; kc += 32) {
    int ko = kc + lg*8;
    bf16x8 ah[2], am[2], al[2], bh[4], bm[4], bl[4];
    #pragma unroll
    for (int m = 0; m < 2; ++m)
      ld3(Ah, Am, Al, R0+16*m+l16, ko, ah[m], am[m], al[m]);
    #pragma unroll
    for (int n = 0; n < 4; ++n) {
      int col = C0+16*n+l16;
      unsigned off = boff(col, ko);
      bh[n] = *(const bf16x8*)(Zh + off);
      bm[n] = *(const bf16x8*)(Zm + off);
      bl[n] = *(const bf16x8*)(ZlG + col*Fc + ko);
    }
    mm6(ah, am, al, bh, bm, bl, acc);
  }
}

__device__ __forceinline__ void split4(f32x4 v, u16x4& hv, u16x4& mv, u16x4& lv) {
  #pragma unroll
  for (int r = 0; r < 4; ++r) {
    unsigned short hb = f2bf_rne(v[r]); float r1 = v[r] - bf2f(hb);
    unsigned short mb = f2bf_rne(r1);   float r2 = r1 - bf2f(mb);
    hv[r] = hb; mv[r] = mb; lv[r] = f2bf_rne(r2);
  }
}
__device__ __forceinline__ void wbA3(char* Ah, char* Am, char* Al,
                                     int col, int row0, f32x4 v) {
  u16x4 hv, mv, lv;
  split4(v, hv, mv, lv);
  unsigned off = boff(col, row0);
  *(u16x4*)(Ah + off) = hv;
  *(u16x4*)(Am + off) = mv;
  *(u16x4*)(Al + off) = lv;
}
__device__ __forceinline__ void wbZ3(char* Zh, char* Zm, unsigned short* __restrict__ ZlG,
                                     int col, int row0, f32x4 v) {
  u16x4 hv, mv, lv;
  split4(v, hv, mv, lv);
  unsigned off = boff(col, row0);
  *(u16x4*)(Zh + off) = hv;
  *(u16x4*)(Zm + off) = mv;
  *(u16x4*)(ZlG + col*Fc + row0) = lv;
}

__global__ __launch_bounds__(512) void newton_ctx_kernel(
    const float* __restrict__ STASn,
    const unsigned short* __restrict__ KhG, const unsigned short* __restrict__ KmG,
    const unsigned short* __restrict__ KlG,
    const float* __restrict__ gmaxv, float* __restrict__ Vout,
    const float* __restrict__ ASg, const float* __restrict__ vg,
    const float* __restrict__ maskg, float* __restrict__ Gpart,
    unsigned short* __restrict__ ZlScr) {
  extern __shared__ char smc[];
  int tid  = threadIdx.x;

  if (blockIdx.x < BHc) {
    // ================= Newton path =================
    char* Ah = smc;
    char* Am = smc + 32768;
    char* Al = smc + 65536;
    char* Zh = smc + 98304;
    char* Zm = smc + 131072;
    int bh = blockIdx.x;
    const float* Kp = STASn + (size_t)bh*Fc*Fc;
    const unsigned short* kh = KhG + (size_t)bh*Fc*Fc;
    const unsigned short* km = KmG + (size_t)bh*Fc*Fc;
    const unsigned short* kl = KlG + (size_t)bh*Fc*Fc;
    unsigned short* ZlG = ZlScr + (size_t)bh*Fc*Fc;
    float gm = 0.f;
    #pragma unroll
    for (int i = 0; i < BHc; ++i) gm = fmaxf(gm, gmaxv[i]);
    float ginv = 1.0f / gm;
    int lane = tid & 63;
    int wid  = tid >> 6;
    int wr = wid >> 1, wc = wid & 1;
    int l16 = lane & 15, lg = lane >> 4;
    int R0 = wr*32, C0 = wc*64;
    int drow0 = lg*4;

    f32x4 vreg[2][4];
    #pragma unroll
    for (int m = 0; m < 2; ++m)
      #pragma unroll
      for (int n = 0; n < 4; ++n) {
        int col = C0 + 16*n + l16;
        #pragma unroll
        for (int r = 0; r < 4; ++r)
          vreg[m][n][r] = Kp[(size_t)(R0 + 16*m + drow0 + r)*Fc + col] * ginv;
        wbA3(Ah, Am, Al, col, R0 + 16*m + drow0, vreg[m][n]);
      }
    __syncthreads();

    f32x4 fin[2][4];
    for (int it = 0; it < 6; ++it) {
      f32x4 acc[2][4];
      // P1: Z = K @ V
      #pragma unroll
      for (int m = 0; m < 2; ++m) for (int n = 0; n < 4; ++n) acc[m][n] = 0.f;
      mm_p1(kh, km, kl, Ah, Am, Al, R0, C0, l16, lg, acc);
      #pragma unroll
      for (int m = 0; m < 2; ++m)
        #pragma unroll
        for (int n = 0; n < 4; ++n)
          wbZ3(Zh, Zm, ZlG, C0 + 16*n + l16, R0 + 16*m + drow0, acc[m][n]);
      __syncthreads();

      // P2: W1 = V @ Z ; fin = 13V - 15W1
      #pragma unroll
      for (int m = 0; m < 2; ++m) for (int n = 0; n < 4; ++n) acc[m][n] = 0.f;
      mm_p234(Ah, Am, Al, Zh, Zm, ZlG, R0, C0, l16, lg, acc);
      #pragma unroll
      for (int m = 0; m < 2; ++m)
        #pragma unroll
        for (int n = 0; n < 4; ++n)
          fin[m][n] = 13.f*vreg[m][n] - 15.f*acc[m][n];
      __syncthreads();
      #pragma unroll
      for (int m = 0; m < 2; ++m)
        #pragma unroll
        for (int n = 0; n < 4; ++n)
          wbA3(Ah, Am, Al, C0 + 16*n + l16, R0 + 16*m + drow0, acc[m][n]);
      __syncthreads();

      // P3: W2 = W1 @ Z ; fin += 7W2
      #pragma unroll
      for (int m = 0; m < 2; ++m) for (int n = 0; n < 4; ++n) acc[m][n] = 0.f;
      mm_p234(Ah, Am, Al, Zh, Zm, ZlG, R0, C0, l16, lg, acc);
      #pragma unroll
      for (int m = 0; m < 2; ++m)
        #pragma unroll
        for (int n = 0; n < 4; ++n)
          fin[m][n] += 7.f*acc[m][n];
      __syncthreads();
      #pragma unroll
      for (int m = 0; m < 2; ++m)
        #pragma unroll
        for (int n = 0; n < 4; ++n)
          wbA3(Ah, Am, Al, C0 + 16*n + l16, R0 + 16*m + drow0, acc[m][n]);
      __syncthreads();

      // P4: W3 = W2 @ Z ; V <- 0.25(fin - W3)
      #pragma unroll
      for (int m = 0; m < 2; ++m) for (int n = 0; n < 4; ++n) acc[m][n] = 0.f;
      mm_p234(Ah, Am, Al, Zh, Zm, ZlG, R0, C0, l16, lg, acc);
      #pragma unroll
      for (int m = 0; m < 2; ++m)
        #pragma unroll
        for (int n = 0; n < 4; ++n) {
          fin[m][n] = 0.25f*(fin[m][n] - acc[m][n]);
          vreg[m][n] = fin[m][n];
        }
      __syncthreads();
      #pragma unroll
      for (int m = 0; m < 2; ++m)
        #pragma unroll
        for (int n = 0; n < 4; ++n)
          wbA3(Ah, Am, Al, C0 + 16*n + l16, R0 + 16*m + drow0, fin[m][n]);
      __syncthreads();
    }

    float* Vo = Vout + (size_t)bh*Fc*Fc;
    #pragma unroll
    for (int m = 0; m < 2; ++m)
      #pragma unroll
      for (int n = 0; n < 4; ++n) {
        int col = C0 + 16*n + l16;
        #pragma unroll
        for (int r = 0; r < 4; ++r)
          Vo[(size_t)(R0 + 16*m + drow0 + r)*Fc + col] = vreg[m][n][r];
      }
  } else {
    // ================= ctx_raw path: G_part = K^T (m^2 v) over a 512-row chunk ====
    float* Ksh = (float*)smc;              // [64][128]
    float* vsh = (float*)(smc + 32768);    // [64][64]
    int id = blockIdx.x - BHc;             // 0..127
    int cbh = id >> 2, chunk = id & 3;
    int cb = cbh >> 3;
    int t0 = chunk * 512;
    int f = tid & 127, g = tid >> 7;       // g in 0..3
    float acc[16];
    #pragma unroll
    for (int j = 0; j < 16; ++j) acc[j] = 0.f;
    for (int sub = 0; sub < 8; ++sub) {
      __syncthreads();
      int ts = t0 + sub*64;
      for (int i = tid; i < 64*32; i += 512) {
        int r = i >> 5, c4 = i & 31;
        *(float4*)&Ksh[r*128 + c4*4] =
            *(const float4*)(ASg + ((size_t)cbh*T2c + Nc + ts + r)*Fc + c4*4);
      }
      for (int i = tid; i < 64*16; i += 512) {
        int r = i >> 4, c4 = i & 15;
        float mk = maskg[cb*Nc + ts + r];
        float m2 = mk*mk;
        float4 x = *(const float4*)(vg + ((size_t)cbh*Nc + ts + r)*Dc + c4*4);
        x.x*=m2; x.y*=m2; x.z*=m2; x.w*=m2;
        *(float4*)&vsh[r*64 + c4*4] = x;
      }
      __syncthreads();
      #pragma unroll 2
      for (int tl = 0; tl < 64; ++tl) {
        float kf = Ksh[tl*128 + f];
        #pragma unroll
        for (int j4 = 0; j4 < 4; ++j4) {
          float4 vv = *(const float4*)&vsh[tl*64 + g*16 + j4*4];
          acc[j4*4+0] += kf*vv.x; acc[j4*4+1] += kf*vv.y;
          acc[j4*4+2] += kf*vv.z; acc[j4*4+3] += kf*vv.w;
        }
      }
    }
    float* gp = Gpart + ((((size_t)cbh*4 + chunk)*128 + f)*64 + g*16);
    #pragma unroll
    for (int j4 = 0; j4 < 4; ++j4)
      *(float4*)(gp + j4*4) = *(const float4*)&acc[j4*4];
  }
}

// ---------------- ctx_fix ----------------
__global__ __launch_bounds__(256) void ctx_fix_kernel(
    const float* __restrict__ Gpart, const float* __restrict__ Vinv,
    const float* __restrict__ Dinv, float* __restrict__ ctxo) {
  __shared__ float DG[128*64];
  __shared__ float Dl[128];
  int bh = blockIdx.x;
  int tid = threadIdx.x;
  if (tid < 128) Dl[tid] = Dinv[bh*Fc + tid];
  __syncthreads();
  for (int i = tid; i < 2048; i += 256) {
    int e = i >> 4, c4 = i & 15;
    const float* g0 = Gpart + ((((size_t)bh*4)*128 + e)*64 + c4*4);
    float4 s0 = *(const float4*)(g0);
    float4 s1 = *(const float4*)(g0 + 8192);
    float4 s2 = *(const float4*)(g0 + 16384);
    float4 s3 = *(const float4*)(g0 + 24576);
    float de = Dl[e];
    float4 o;
    o.x = (s0.x+s1.x+s2.x+s3.x)*de;
    o.y = (s0.y+s1.y+s2.y+s3.y)*de;
    o.z = (s0.z+s1.z+s2.z+s3.z)*de;
    o.w = (s0.w+s1.w+s2.w+s3.w)*de;
    *(float4*)&DG[e*64 + c4*4] = o;
  }
  __syncthreads();
  int f = tid & 127, half = tid >> 7;
  float acc[32];
  #pragma unroll
  for (int j = 0; j < 32; ++j) acc[j] = 0.f;
  for (int e = 0; e < 128; ++e) {
    float s = Vinv[(size_t)bh*Fc*Fc + (size_t)e*Fc + f];
    #pragma unroll
    for (int j4 = 0; j4 < 8; ++j4) {
      float4 dg = *(const float4*)&DG[e*64 + half*32 + j4*4];
      acc[j4*4+0] += s*dg.x; acc[j4*4+1] += s*dg.y;
      acc[j4*4+2] += s*dg.z; acc[j4*4+3] += s*dg.w;
    }
  }
  float df = Dl[f];
  float* op = ctxo + (size_t)bh*Fc*Dc + f*Dc + half*32;
  #pragma unroll
  for (int j4 = 0; j4 < 8; ++j4) {
    float4 o;
    o.x = acc[j4*4+0]*df; o.y = acc[j4*4+1]*df;
    o.z = acc[j4*4+2]*df; o.w = acc[j4*4+3]*df;
    *(float4*)(op + j4*4) = o;
  }
}

// ---------------- out = Q @ context (VALU) ----------------
__global__ __launch_bounds__(256) void out_kernel(
    const float* __restrict__ AS, const float* __restrict__ ctx,
    float* __restrict__ out) {
  extern __shared__ float smo[];
  float* Asq = smo;            // [64][132]
  float* Cs  = smo + 64*132;   // [128][64]
  int bh = blockIdx.y;
  int row0 = blockIdx.x * 64;
  int tid = threadIdx.x;
  int tr = tid >> 4, tc = tid & 15;
  for (int i = tid; i < 64*32; i += 256) {
    int r = i >> 5, kq = i & 31;
    *(float4*)&Asq[r*132 + kq*4] =
        *(const float4*)(AS + ((size_t)bh*T2c + row0 + r)*Fc + kq*4);
  }
  for (int i = tid; i < 128*16; i += 256) {
    int r = i >> 4, kq = i & 15;
    *(float4*)&Cs[r*64 + kq*4] =
        *(const float4*)(ctx + (size_t)bh*Fc*Dc + r*Dc + kq*4);
  }
  __syncthreads();
  float acc[4][4] = {};
  #pragma unroll 2
  for (int kk = 0; kk < Fc; ++kk) {
    float4 bv = *(const float4*)&Cs[kk*64 + tc*4];
    float a0 = Asq[(tr*4+0)*132 + kk];
    float a1 = Asq[(tr*4+1)*132 + kk];
    float a2 = Asq[(tr*4+2)*132 + kk];
    float a3 = Asq[(tr*4+3)*132 + kk];
    acc[0][0] += a0*bv.x; acc[0][1] += a0*bv.y; acc[0][2] += a0*bv.z; acc[0][3] += a0*bv.w;
    acc[1][0] += a1*bv.x; acc[1][1] += a1*bv.y; acc[1][2] += a1*bv.z; acc[1][3] += a1*bv.w;
    acc[2][0] += a2*bv.x; acc[2][1] += a2*bv.y; acc[2][2] += a2*bv.z; acc[2][3] += a2*bv.w;
    acc[3][0] += a3*bv.x; acc[3][1] += a3*bv.y; acc[3][2] += a3*bv.z; acc[3][3] += a3*bv.w;
  }
  #pragma unroll
  for (int i = 0; i < 4; ++i) {
    float4 o;
    o.x = acc[i][0]; o.y = acc[i][1]; o.z = acc[i][2]; o.w = acc[i][3];
    *(float4*)(out + ((size_t)bh*Nc + row0 + tr*4 + i)*Dc + tc*4) = o;
  }
}

extern "C" void kernel_launch(void* const* d_in, const int* in_sizes, int n_in,
                              void* d_out, int out_size, void* d_ws, size_t ws_size,
                              hipStream_t stream) {
  const float* q    = (const float*)d_in[0];
  const float* k    = (const float*)d_in[1];
  const float* v    = (const float*)d_in[2];
  const float* mask = (const float*)d_in[3];
  const float* sign = (const float*)d_in[4];
  const int*   sketch = (const int*)d_in[5];
  float* out = (float*)d_out;
  float* ws  = (float*)d_ws;

  unsigned short* xsh = (unsigned short*)(ws + OFF_XSH);
  unsigned short* xsm = (unsigned short*)(ws + OFF_XSM);
  unsigned short* xsl = (unsigned short*)(ws + OFF_XSL);
  unsigned short* kh  = (unsigned short*)(ws + OFF_KH);
  unsigned short* km  = (unsigned short*)(ws + OFF_KM);
  unsigned short* kl  = (unsigned short*)(ws + OFF_KL);
  unsigned short* zsc = (unsigned short*)(ws + OFF_ZSC);

  prep_kernel<<<D1_BLOCKS + BHc*Jc*16/256, 256, 0, stream>>>(
      q, k, mask, sketch, ws + OFF_DIAG1, xsh, xsm, xsl, ws + OFF_DIAG2);
  as_mfma_kernel<<<dim3(T2c/128, BHc), 512, 102912, stream>>>(q, k, mask, xsh, xsm, xsl,
      ws + OFF_DIAG1, ws + OFF_DIAG2, sign, ws + OFF_AS);
  stas_kernel<<<BHc, 256, 128*129*sizeof(float), stream>>>(ws + OFF_AS, sketch, sign,
      ws + OFF_STASN, ws + OFF_DINV, kh, km, kl, ws + OFF_GMAX);
  newton_ctx_kernel<<<BHc + 128, 512, 163840, stream>>>(ws + OFF_STASN, kh, km, kl,
      ws + OFF_GMAX, ws + OFF_VBUF, ws + OFF_AS, v, mask, ws + OFF_GPART, zsc);
  ctx_fix_kernel<<<BHc, 256, 0, stream>>>(ws + OFF_GPART, ws + OFF_VBUF,
      ws + OFF_DINV, ws + OFF_CTX);
  out_kernel<<<dim3(Nc/64, BHc), 256, (64*132 + 128*64)*sizeof(float), stream>>>(
      ws + OFF_AS, ws + OFF_CTX, out);
}

// Round 17
// 321.889 us; speedup vs baseline: 1.0665x; 1.0058x over previous
//
#include <hip/hip_runtime.h>

constexpr int Bc = 4, Hc = 8, Nc = 2048, Dc = 64, Fc = 128, Mc = 4;
constexpr int BHc = Bc*Hc;        // 32
constexpr int T2c = 2*Nc;         // 4096
constexpr int Jc  = Mc*Fc;        // 512
constexpr float DNORM = 0.4204482076268573f;   // 32^-0.25

// workspace offsets (in floats)
constexpr size_t OFF_AS    = 0;                                 // 16777216
constexpr size_t OFF_XSH   = OFF_AS    + (size_t)BHc*T2c*Fc;    // xs h-plane (ushort)
constexpr size_t OFF_XSM   = OFF_XSH   + (size_t)BHc*Jc*Dc/2;
constexpr size_t OFF_XSL   = OFF_XSM   + (size_t)BHc*Jc*Dc/2;
constexpr size_t OFF_DIAG1 = OFF_XSL   + (size_t)BHc*Jc*Dc/2;   // (unused, kept for layout)
constexpr size_t OFF_DIAG2 = OFF_DIAG1 + (size_t)BHc*T2c;
constexpr size_t OFF_STASN = OFF_DIAG2 + (size_t)BHc*Jc;
constexpr size_t OFF_VBUF  = OFF_STASN + (size_t)BHc*Fc*Fc;
constexpr size_t OFF_DINV  = OFF_VBUF  + (size_t)BHc*Fc*Fc;
constexpr size_t OFF_GMAX  = OFF_DINV  + (size_t)BHc*Fc;        // gmaxv[32] floats
constexpr size_t OFF_CTX   = OFF_GMAX  + 64;
constexpr size_t OFF_KH    = OFF_CTX   + (size_t)BHc*Fc*Dc;     // K h-plane (ushort)
constexpr size_t OFF_KM    = OFF_KH    + (size_t)BHc*Fc*Fc/2;
constexpr size_t OFF_KL    = OFF_KM    + (size_t)BHc*Fc*Fc/2;
// reuse of xs-plane region (dead after as_mfma):
constexpr size_t OFF_GPART = OFF_XSH;                           // [BHc][4][128][64] floats
constexpr size_t OFF_ZSC   = OFF_GPART + (size_t)BHc*4*128*64;  // Zl scratch: BHc*16384 ushort

typedef __attribute__((ext_vector_type(8))) short bf16x8;
typedef __attribute__((ext_vector_type(4))) float f32x4;
typedef __attribute__((ext_vector_type(4))) unsigned short u16x4;

__device__ __forceinline__ unsigned short f2bf_rne(float x) {
  unsigned int u = __float_as_uint(x);
  u += 0x7fff + ((u >> 16) & 1);
  return (unsigned short)(u >> 16);
}
__device__ __forceinline__ float bf2f(unsigned short h) {
  return __uint_as_float(((unsigned int)h) << 16);
}

// ---------------- gather -> pre-split bf16 h/m/l planes + diag2 (local, bit-identical) ----------------
__global__ __launch_bounds__(256) void gather_kernel(
    const float* __restrict__ q, const float* __restrict__ k,
    const float* __restrict__ mask, const int* __restrict__ sketch,
    unsigned short* __restrict__ xsh, unsigned short* __restrict__ xsm,
    unsigned short* __restrict__ xsl, float* __restrict__ diag2) {
  int gid = blockIdx.x*256 + threadIdx.x;
  int kq  = gid & 15;
  int idx = gid >> 4;
  int j   = idx & (Jc - 1);
  int bh  = idx >> 9;
  int b   = bh >> 3;
  int t   = sketch[b*Jc + j];
  int tn  = (t < Nc) ? t : t - Nc;
  const float* src = ((t < Nc) ? q : k) + ((size_t)bh*Nc + tn)*Dc;
  float sc = DNORM * mask[b*Nc + tn];
  float4 x = *(const float4*)(src + kq*4);
  float s = x.x*x.x + x.y*x.y + x.z*x.z + x.w*x.w;
  s += __shfl_xor(s, 1);
  s += __shfl_xor(s, 2);
  s += __shfl_xor(s, 4);
  s += __shfl_xor(s, 8);
  float xv[4] = {x.x*sc, x.y*sc, x.z*sc, x.w*sc};
  u16x4 hh, mm_, ll;
  #pragma unroll
  for (int jj = 0; jj < 4; ++jj) {
    unsigned short h = f2bf_rne(xv[jj]);
    float r1 = xv[jj] - bf2f(h);
    unsigned short m = f2bf_rne(r1);
    float r2 = r1 - bf2f(m);
    hh[jj] = h; mm_[jj] = m; ll[jj] = f2bf_rne(r2);
  }
  *(u16x4*)(xsh + (size_t)idx*Dc + kq*4) = hh;
  *(u16x4*)(xsm + (size_t)idx*Dc + kq*4) = mm_;
  *(u16x4*)(xsl + (size_t)idx*Dc + kq*4) = ll;
  if (kq == 0) diag2[idx] = 0.5f * sc * sc * s;
}

// ---- swizzled [r][64]-ushort plane offset (byte): conflict-free b128 reads ----
__device__ __forceinline__ unsigned poff(int r, int ke) {
  unsigned byte = ((unsigned)r << 7) | ((unsigned)ke << 1);
  return byte ^ (((unsigned)(r & 7)) << 4);
}

// ---------------- AS GEMM via MFMA: 128x128 tile, 8 waves, LDS-staged A&B ----------------
// d1s is computed IN the A-staging loop, bit-identical to the old diag1_kernel:
// same 16-lane groups (i%16==kq, rows on 16-lane boundaries), same shfl_xor
// 1/2/4/8 tree, same 0.5*sc*sc*s. Deletes the whole diag1 pass + 64MB re-read.
__global__ __launch_bounds__(512) void as_mfma_kernel(
    const float* __restrict__ q, const float* __restrict__ k,
    const float* __restrict__ mask,
    const unsigned short* __restrict__ xsh, const unsigned short* __restrict__ xsm,
    const unsigned short* __restrict__ xsl,
    const float* __restrict__ diag2,
    const float* __restrict__ sign, float* __restrict__ AS) {
  extern __shared__ char sma[];
  char* Ah = sma;                 // [128][64] ushort, poff-swizzled (16KB each)
  char* Am = sma + 16384;
  char* Al = sma + 32768;
  char* Bh = sma + 49152;
  char* Bm = sma + 65536;
  char* Bl = sma + 81920;
  float* d1s = (float*)(sma + 98304);    // [128]
  float* d2s = (float*)(sma + 98816);    // [4][128]
  float* sgs = (float*)(sma + 100864);   // [4][128]
  int bh = blockIdx.y, b = bh >> 3;
  int t0 = blockIdx.x * 128;
  int tid = threadIdx.x;
  int lane = tid & 63, wid = tid >> 6;   // 8 waves
  int wr = wid >> 1, wc = wid & 1;
  int l16 = lane & 15, lg = lane >> 4;
  int R0 = wr*32, C0 = wc*64;

  for (int i = tid; i < 128*16; i += 512) {
    int r = i >> 4, kq = i & 15;
    int t = t0 + r;
    int tn = (t < Nc) ? t : t - Nc;
    const float* src = ((t < Nc) ? q : k) + ((size_t)bh*Nc + tn)*Dc + kq*4;
    float sc = DNORM * mask[b*Nc + tn];
    float4 x = *(const float4*)src;
    // d1 for this row, bit-identical to diag1_kernel's reduction
    float s = x.x*x.x + x.y*x.y + x.z*x.z + x.w*x.w;
    s += __shfl_xor(s, 1);
    s += __shfl_xor(s, 2);
    s += __shfl_xor(s, 4);
    s += __shfl_xor(s, 8);
    if (kq == 0) d1s[r] = 0.5f * sc * sc * s;
    float xv[4] = {x.x*sc, x.y*sc, x.z*sc, x.w*sc};
    u16x4 hv, mv, lv;
    #pragma unroll
    for (int jj = 0; jj < 4; ++jj) {
      unsigned short h = f2bf_rne(xv[jj]);
      float r1 = xv[jj] - bf2f(h);
      unsigned short m = f2bf_rne(r1);
      float r2 = r1 - bf2f(m);
      hv[jj] = h; mv[jj] = m; lv[jj] = f2bf_rne(r2);
    }
    unsigned off = poff(r, kq*4);
    *(u16x4*)(Ah + off) = hv;
    *(u16x4*)(Am + off) = mv;
    *(u16x4*)(Al + off) = lv;
  }
  for (int i = tid; i < 512; i += 512) {
    d2s[i] = diag2[bh*Jc + i];
    sgs[i] = sign[b*Jc + i];
  }

  const unsigned short* xhh = xsh + (size_t)bh*Jc*Dc;
  const unsigned short* xmm = xsm + (size_t)bh*Jc*Dc;
  const unsigned short* xll = xsl + (size_t)bh*Jc*Dc;
  f32x4 oa[2][4];
  #pragma unroll
  for (int m = 0; m < 2; ++m)
    #pragma unroll
    for (int n = 0; n < 4; ++n) oa[m][n] = 0.f;

  for (int m = 0; m < Mc; ++m) {
    __syncthreads();
    for (int i = tid; i < 128*16; i += 512) {
      int c = i >> 4, k4 = i & 15;
      size_t p = (size_t)(m*Fc + c)*Dc + k4*4;
      unsigned off = poff(c, k4*4);
      *(u16x4*)(Bh + off) = *(const u16x4*)(xhh + p);
      *(u16x4*)(Bm + off) = *(const u16x4*)(xmm + p);
      *(u16x4*)(Bl + off) = *(const u16x4*)(xll + p);
    }
    __syncthreads();

    f32x4 acc[2][4];
    #pragma unroll
    for (int mm = 0; mm < 2; ++mm)
      #pragma unroll
      for (int nn = 0; nn < 4; ++nn) acc[mm][nn] = 0.f;
    #pragma unroll
    for (int kc = 0; kc < Dc; kc += 32) {
      int ko = kc + lg*8;
      bf16x8 ah[2], am2[2], al2[2], bhv[4], bmv[4], blv[4];
      #pragma unroll
      for (int mm = 0; mm < 2; ++mm) {
        unsigned off = poff(R0+16*mm+l16, ko);
        ah[mm]  = *(const bf16x8*)(Ah + off);
        am2[mm] = *(const bf16x8*)(Am + off);
        al2[mm] = *(const bf16x8*)(Al + off);
      }
      #pragma unroll
      for (int nn = 0; nn < 4; ++nn) {
        unsigned off = poff(C0+16*nn+l16, ko);
        bhv[nn] = *(const bf16x8*)(Bh + off);
        bmv[nn] = *(const bf16x8*)(Bm + off);
        blv[nn] = *(const bf16x8*)(Bl + off);
      }
      #pragma unroll
      for (int mm = 0; mm < 2; ++mm)
        #pragma unroll
        for (int nn = 0; nn < 4; ++nn) {
          acc[mm][nn] = __builtin_amdgcn_mfma_f32_16x16x32_bf16(am2[mm], bmv[nn], acc[mm][nn], 0,0,0);
          acc[mm][nn] = __builtin_amdgcn_mfma_f32_16x16x32_bf16(ah[mm],  blv[nn], acc[mm][nn], 0,0,0);
          acc[mm][nn] = __builtin_amdgcn_mfma_f32_16x16x32_bf16(al2[mm], bhv[nn], acc[mm][nn], 0,0,0);
          acc[mm][nn] = __builtin_amdgcn_mfma_f32_16x16x32_bf16(ah[mm],  bmv[nn], acc[mm][nn], 0,0,0);
          acc[mm][nn] = __builtin_amdgcn_mfma_f32_16x16x32_bf16(am2[mm], bhv[nn], acc[mm][nn], 0,0,0);
          acc[mm][nn] = __builtin_amdgcn_mfma_f32_16x16x32_bf16(ah[mm],  bhv[nn], acc[mm][nn], 0,0,0);
        }
    }
    #pragma unroll
    for (int mm = 0; mm < 2; ++mm)
      #pragma unroll
      for (int nn = 0; nn < 4; ++nn) {
        int c = C0 + 16*nn + l16;
        float d2v = d2s[m*Fc + c], sg = sgs[m*Fc + c];
        #pragma unroll
        for (int r = 0; r < 4; ++r) {
          int row = R0 + 16*mm + 4*lg + r;
          oa[mm][nn][r] += sg * __expf(acc[mm][nn][r] - d1s[row] - d2v);
        }
      }
  }
  #pragma unroll
  for (int mm = 0; mm < 2; ++mm)
    #pragma unroll
    for (int nn = 0; nn < 4; ++nn) {
      int c = C0 + 16*nn + l16;
      #pragma unroll
      for (int r = 0; r < 4; ++r) {
        int row = R0 + 16*mm + 4*lg + r;
        AS[((size_t)bh*T2c + t0 + row)*Fc + c] = oa[mm][nn][r];
      }
    }
}

// ---------------- STAS build + normalize + K planes + per-bh colsum max ----------------
__global__ __launch_bounds__(256) void stas_kernel(
    const float* __restrict__ AS, const int* __restrict__ sketch,
    const float* __restrict__ sign,
    float* __restrict__ STASn, float* __restrict__ Dinv,
    unsigned short* __restrict__ Kh, unsigned short* __restrict__ Km,
    unsigned short* __restrict__ Kl,
    float* __restrict__ gmaxv) {
  extern __shared__ float stas[];   // [128][129]
  __shared__ int   Ssh[Jc];
  __shared__ float sgn[Jc];
  __shared__ float Dl[Fc];
  __shared__ float red[Fc];
  int bh = blockIdx.x;
  int b  = bh >> 3;
  int tid = threadIdx.x;
  for (int i = tid; i < Jc; i += 256) {
    Ssh[i] = sketch[b*Jc + i];
    sgn[i] = sign[b*Jc + i];
  }
  __syncthreads();
  for (int i = tid; i < Fc*Fc; i += 256) {
    int dd = i >> 7, e = i & 127;
    float vsum = 0.f;
    #pragma unroll
    for (int m = 0; m < Mc; ++m) {
      int t = Ssh[m*Fc + dd];
      vsum += sgn[m*Fc + dd] * AS[((size_t)bh*T2c + t)*Fc + e];
    }
    if (dd == e) vsum += 0.1f;
    stas[dd*129 + e] = vsum;
  }
  __syncthreads();
  if (tid < Fc) {
    float s = 0.f;
    for (int e = 0; e < Fc; ++e) s += stas[tid*129 + e];
    float di = 1.0f / sqrtf(s);
    Dl[tid] = di;
    Dinv[bh*Fc + tid] = di;
  }
  __syncthreads();
  for (int i = tid; i < Fc*Fc; i += 256) {
    int dd = i >> 7, e = i & 127;
    float vv = stas[dd*129 + e] * Dl[dd] * Dl[e];
    stas[dd*129 + e] = vv;
    STASn[(size_t)bh*Fc*Fc + i] = vv;
    unsigned short hb = f2bf_rne(vv); float r1 = vv - bf2f(hb);
    unsigned short mb = f2bf_rne(r1); float r2 = r1 - bf2f(mb);
    Kh[(size_t)bh*Fc*Fc + i] = hb;
    Km[(size_t)bh*Fc*Fc + i] = mb;
    Kl[(size_t)bh*Fc*Fc + i] = f2bf_rne(r2);
  }
  __syncthreads();
  if (tid < Fc) {
    float s = 0.f;
    for (int dd = 0; dd < Fc; ++dd) s += stas[dd*129 + tid];
    red[tid] = s;
  }
  __syncthreads();
  if (tid == 0) {
    float mx = 0.f;
    for (int e = 0; e < Fc; ++e) mx = fmaxf(mx, red[e]);
    gmaxv[bh] = mx;          // plain store; newton reduces max over 32 slots
  }
}

// ---------------- Newton-Schulz (round-8 body) + fused ctx_raw ----------------
__device__ __forceinline__ unsigned boff(int brow, int ke) {
  unsigned byte = ((unsigned)brow << 8) | ((unsigned)ke << 1);
  return byte ^ (((unsigned)(brow & 7)) << 4);
}

__device__ __forceinline__ void mm6(const bf16x8 ah[2], const bf16x8 am[2], const bf16x8 al[2],
                                    const bf16x8 bh[4], const bf16x8 bm[4], const bf16x8 bl[4],
                                    f32x4 acc[2][4]) {
  #pragma unroll
  for (int m = 0; m < 2; ++m)
    #pragma unroll
    for (int n = 0; n < 4; ++n) {
      acc[m][n] = __builtin_amdgcn_mfma_f32_16x16x32_bf16(am[m], bm[n], acc[m][n], 0,0,0);
      acc[m][n] = __builtin_amdgcn_mfma_f32_16x16x32_bf16(ah[m], bl[n], acc[m][n], 0,0,0);
      acc[m][n] = __builtin_amdgcn_mfma_f32_16x16x32_bf16(al[m], bh[n], acc[m][n], 0,0,0);
      acc[m][n] = __builtin_amdgcn_mfma_f32_16x16x32_bf16(ah[m], bm[n], acc[m][n], 0,0,0);
      acc[m][n] = __builtin_amdgcn_mfma_f32_16x16x32_bf16(am[m], bh[n], acc[m][n], 0,0,0);
      acc[m][n] = __builtin_amdgcn_mfma_f32_16x16x32_bf16(ah[m], bh[n], acc[m][n], 0,0,0);
    }
}

__device__ __forceinline__ void ld3(const char* Ph, const char* Pm, const char* Pl,
                                    int brow, int ko, bf16x8& h, bf16x8& m, bf16x8& l) {
  unsigned off = boff(brow, ko);
  h = *(const bf16x8*)(Ph + off);
  m = *(const bf16x8*)(Pm + off);
  l = *(const bf16x8*)(Pl + off);
}

__device__ __forceinline__ void mm_p1(
    const unsigned short* __restrict__ kh, const unsigned short* __restrict__ km,
    const unsigned short* __restrict__ kl,
    const char* Ah, const char* Am, const char* Al,
    int R0, int C0, int l16, int lg, f32x4 acc[2][4]) {
  #pragma unroll 2
  for (int kc = 0; kc < Fc; kc += 32) {
    int ko = kc + lg*8;
    bf16x8 ah[2], am[2], al[2], bh[4], bm[4], bl[4];
    #pragma unroll
    for (int m = 0; m < 2; ++m) {
      size_t p = (size_t)(R0+16*m+l16)*Fc + ko;
      ah[m] = *(const bf16x8*)(kh + p);
      am[m] = *(const bf16x8*)(km + p);
      al[m] = *(const bf16x8*)(kl + p);
    }
    #pragma unroll
    for (int n = 0; n < 4; ++n)
      ld3(Ah, Am, Al, C0+16*n+l16, ko, bh[n], bm[n], bl[n]);
    mm6(ah, am, al, bh, bm, bl, acc);
  }
}

__device__ __forceinline__ void mm_p234(
    const char* Ah, const char* Am, const char* Al,
    const char* Zh, const char* Zm, const unsigned short* __restrict__ ZlG,
    int R0, int C0, int l16, int lg, f32x4 acc[2][4]) {
  #pragma unroll 1
  for (int kc = 0; kc < Fc; kc += 32) {
    int ko = kc + lg*8;
    bf16x8 ah[2], am[2], al[2], bh[4], bm[4], bl[4];
    #pragma unroll
    for (int m = 0; m < 2; ++m)
      ld3(Ah, Am, Al, R0+16*m+l16, ko, ah[m], am[m], al[m]);
    #pragma unroll
    for (int n = 0; n < 4; ++n) {
      int col = C0+16*n+l16;
      unsigned off = boff(col, ko);
      bh[n] = *(const bf16x8*)(Zh + off);
      bm[n] = *(const bf16x8*)(Zm + off);
      bl[n] = *(const bf16x8*)(ZlG + col*Fc + ko);
    }
    mm6(ah, am, al, bh, bm, bl, acc);
  }
}

__device__ __forceinline__ void split4(f32x4 v, u16x4& hv, u16x4& mv, u16x4& lv) {
  #pragma unroll
  for (int r = 0; r < 4; ++r) {
    unsigned short hb = f2bf_rne(v[r]); float r1 = v[r] - bf2f(hb);
    unsigned short mb = f2bf_rne(r1);   float r2 = r1 - bf2f(mb);
    hv[r] = hb; mv[r] = mb; lv[r] = f2bf_rne(r2);
  }
}
__device__ __forceinline__ void wbA3(char* Ah, char* Am, char* Al,
                                     int col, int row0, f32x4 v) {
  u16x4 hv, mv, lv;
  split4(v, hv, mv, lv);
  unsigned off = boff(col, row0);
  *(u16x4*)(Ah + off) = hv;
  *(u16x4*)(Am + off) = mv;
  *(u16x4*)(Al + off) = lv;
}
__device__ __forceinline__ void wbZ3(char* Zh, char* Zm, unsigned short* __restrict__ ZlG,
                                     int col, int row0, f32x4 v) {
  u16x4 hv, mv, lv;
  split4(v, hv, mv, lv);
  unsigned off = boff(col, row0);
  *(u16x4*)(Zh + off) = hv;
  *(u16x4*)(Zm + off) = mv;
  *(u16x4*)(ZlG + col*Fc + row0) = lv;
}

__global__ __launch_bounds__(512) void newton_ctx_kernel(
    const float* __restrict__ STASn,
    const unsigned short* __restrict__ KhG, const unsigned short* __restrict__ KmG,
    const unsigned short* __restrict__ KlG,
    const float* __restrict__ gmaxv, float* __restrict__ Vout,
    const float* __restrict__ ASg, const float* __restrict__ vg,
    const float* __restrict__ maskg, float* __restrict__ Gpart,
    unsigned short* __restrict__ ZlScr) {
  extern __shared__ char smc[];
  int tid  = threadIdx.x;

  if (blockIdx.x < BHc) {
    // ================= Newton path =================
    char* Ah = smc;
    char* Am = smc + 32768;
    char* Al = smc + 65536;
    char* Zh = smc + 98304;
    char* Zm = smc + 131072;
    int bh = blockIdx.x;
    const float* Kp = STASn + (size_t)bh*Fc*Fc;
    const unsigned short* kh = KhG + (size_t)bh*Fc*Fc;
    const unsigned short* km = KmG + (size_t)bh*Fc*Fc;
    const unsigned short* kl = KlG + (size_t)bh*Fc*Fc;
    unsigned short* ZlG = ZlScr + (size_t)bh*Fc*Fc;
    float gm = 0.f;
    #pragma unroll
    for (int i = 0; i < BHc; ++i) gm = fmaxf(gm, gmaxv[i]);
    float ginv = 1.0f / gm;
    int lane = tid & 63;
    int wid  = tid >> 6;
    int wr = wid >> 1, wc = wid & 1;
    int l16 = lane & 15, lg = lane >> 4;
    int R0 = wr*32, C0 = wc*64;
    int drow0 = lg*4;

    f32x4 vreg[2][4];
    #pragma unroll
    for (int m = 0; m < 2; ++m)
      #pragma unroll
      for (int n = 0; n < 4; ++n) {
        int col = C0 + 16*n + l16;
        #pragma unroll
        for (int r = 0; r < 4; ++r)
          vreg[m][n][r] = Kp[(size_t)(R0 + 16*m + drow0 + r)*Fc + col] * ginv;
        wbA3(Ah, Am, Al, col, R0 + 16*m + drow0, vreg[m][n]);
      }
    __syncthreads();

    f32x4 fin[2][4];
    for (int it = 0; it < 6; ++it) {
      f32x4 acc[2][4];
      // P1: Z = K @ V
      #pragma unroll
      for (int m = 0; m < 2; ++m) for (int n = 0; n < 4; ++n) acc[m][n] = 0.f;
      mm_p1(kh, km, kl, Ah, Am, Al, R0, C0, l16, lg, acc);
      #pragma unroll
      for (int m = 0; m < 2; ++m)
        #pragma unroll
        for (int n = 0; n < 4; ++n)
          wbZ3(Zh, Zm, ZlG, C0 + 16*n + l16, R0 + 16*m + drow0, acc[m][n]);
      __syncthreads();

      // P2: W1 = V @ Z ; fin = 13V - 15W1
      #pragma unroll
      for (int m = 0; m < 2; ++m) for (int n = 0; n < 4; ++n) acc[m][n] = 0.f;
      mm_p234(Ah, Am, Al, Zh, Zm, ZlG, R0, C0, l16, lg, acc);
      #pragma unroll
      for (int m = 0; m < 2; ++m)
        #pragma unroll
        for (int n = 0; n < 4; ++n)
          fin[m][n] = 13.f*vreg[m][n] - 15.f*acc[m][n];
      __syncthreads();
      #pragma unroll
      for (int m = 0; m < 2; ++m)
        #pragma unroll
        for (int n = 0; n < 4; ++n)
          wbA3(Ah, Am, Al, C0 + 16*n + l16, R0 + 16*m + drow0, acc[m][n]);
      __syncthreads();

      // P3: W2 = W1 @ Z ; fin += 7W2
      #pragma unroll
      for (int m = 0; m < 2; ++m) for (int n = 0; n < 4; ++n) acc[m][n] = 0.f;
      mm_p234(Ah, Am, Al, Zh, Zm, ZlG, R0, C0, l16, lg, acc);
      #pragma unroll
      for (int m = 0; m < 2; ++m)
        #pragma unroll
        for (int n = 0; n < 4; ++n)
          fin[m][n] += 7.f*acc[m][n];
      __syncthreads();
      #pragma unroll
      for (int m = 0; m < 2; ++m)
        #pragma unroll
        for (int n = 0; n < 4; ++n)
          wbA3(Ah, Am, Al, C0 + 16*n + l16, R0 + 16*m + drow0, acc[m][n]);
      __syncthreads();

      // P4: W3 = W2 @ Z ; V <- 0.25(fin - W3)
      #pragma unroll
      for (int m = 0; m < 2; ++m) for (int n = 0; n < 4; ++n) acc[m][n] = 0.f;
      mm_p234(Ah, Am, Al, Zh, Zm, ZlG, R0, C0, l16, lg, acc);
      #pragma unroll
      for (int m = 0; m < 2; ++m)
        #pragma unroll
        for (int n = 0; n < 4; ++n) {
          fin[m][n] = 0.25f*(fin[m][n] - acc[m][n]);
          vreg[m][n] = fin[m][n];
        }
      __syncthreads();
      #pragma unroll
      for (int m = 0; m < 2; ++m)
        #pragma unroll
        for (int n = 0; n < 4; ++n)
          wbA3(Ah, Am, Al, C0 + 16*n + l16, R0 + 16*m + drow0, fin[m][n]);
      __syncthreads();
    }

    float* Vo = Vout + (size_t)bh*Fc*Fc;
    #pragma unroll
    for (int m = 0; m < 2; ++m)
      #pragma unroll
      for (int n = 0; n < 4; ++n) {
        int col = C0 + 16*n + l16;
        #pragma unroll
        for (int r = 0; r < 4; ++r)
          Vo[(size_t)(R0 + 16*m + drow0 + r)*Fc + col] = vreg[m][n][r];
      }
  } else {
    // ================= ctx_raw path: G_part = K^T (m^2 v) over a 512-row chunk ====
    float* Ksh = (float*)smc;              // [64][128]
    float* vsh = (float*)(smc + 32768);    // [64][64]
    int id = blockIdx.x - BHc;             // 0..127
    int cbh = id >> 2, chunk = id & 3;
    int cb = cbh >> 3;
    int t0 = chunk * 512;
    int f = tid & 127, g = tid >> 7;       // g in 0..3
    float acc[16];
    #pragma unroll
    for (int j = 0; j < 16; ++j) acc[j] = 0.f;
    for (int sub = 0; sub < 8; ++sub) {
      __syncthreads();
      int ts = t0 + sub*64;
      for (int i = tid; i < 64*32; i += 512) {
        int r = i >> 5, c4 = i & 31;
        *(float4*)&Ksh[r*128 + c4*4] =
            *(const float4*)(ASg + ((size_t)cbh*T2c + Nc + ts + r)*Fc + c4*4);
      }
      for (int i = tid; i < 64*16; i += 512) {
        int r = i >> 4, c4 = i & 15;
        float mk = maskg[cb*Nc + ts + r];
        float m2 = mk*mk;
        float4 x = *(const float4*)(vg + ((size_t)cbh*Nc + ts + r)*Dc + c4*4);
        x.x*=m2; x.y*=m2; x.z*=m2; x.w*=m2;
        *(float4*)&vsh[r*64 + c4*4] = x;
      }
      __syncthreads();
      #pragma unroll 2
      for (int tl = 0; tl < 64; ++tl) {
        float kf = Ksh[tl*128 + f];
        #pragma unroll
        for (int j4 = 0; j4 < 4; ++j4) {
          float4 vv = *(const float4*)&vsh[tl*64 + g*16 + j4*4];
          acc[j4*4+0] += kf*vv.x; acc[j4*4+1] += kf*vv.y;
          acc[j4*4+2] += kf*vv.z; acc[j4*4+3] += kf*vv.w;
        }
      }
    }
    float* gp = Gpart + ((((size_t)cbh*4 + chunk)*128 + f)*64 + g*16);
    #pragma unroll
    for (int j4 = 0; j4 < 4; ++j4)
      *(float4*)(gp + j4*4) = *(const float4*)&acc[j4*4];
  }
}

// ---------------- ctx_fix ----------------
__global__ __launch_bounds__(256) void ctx_fix_kernel(
    const float* __restrict__ Gpart, const float* __restrict__ Vinv,
    const float* __restrict__ Dinv, float* __restrict__ ctxo) {
  __shared__ float DG[128*64];
  __shared__ float Dl[128];
  int bh = blockIdx.x;
  int tid = threadIdx.x;
  if (tid < 128) Dl[tid] = Dinv[bh*Fc + tid];
  __syncthreads();
  for (int i = tid; i < 2048; i += 256) {
    int e = i >> 4, c4 = i & 15;
    const float* g0 = Gpart + ((((size_t)bh*4)*128 + e)*64 + c4*4);
    float4 s0 = *(const float4*)(g0);
    float4 s1 = *(const float4*)(g0 + 8192);
    float4 s2 = *(const float4*)(g0 + 16384);
    float4 s3 = *(const float4*)(g0 + 24576);
    float de = Dl[e];
    float4 o;
    o.x = (s0.x+s1.x+s2.x+s3.x)*de;
    o.y = (s0.y+s1.y+s2.y+s3.y)*de;
    o.z = (s0.z+s1.z+s2.z+s3.z)*de;
    o.w = (s0.w+s1.w+s2.w+s3.w)*de;
    *(float4*)&DG[e*64 + c4*4] = o;
  }
  __syncthreads();
  int f = tid & 127, half = tid >> 7;
  float acc[32];
  #pragma unroll
  for (int j = 0; j < 32; ++j) acc[j] = 0.f;
  for (int e = 0; e < 128; ++e) {
    float s = Vinv[(size_t)bh*Fc*Fc + (size_t)e*Fc + f];
    #pragma unroll
    for (int j4 = 0; j4 < 8; ++j4) {
      float4 dg = *(const float4*)&DG[e*64 + half*32 + j4*4];
      acc[j4*4+0] += s*dg.x; acc[j4*4+1] += s*dg.y;
      acc[j4*4+2] += s*dg.z; acc[j4*4+3] += s*dg.w;
    }
  }
  float df = Dl[f];
  float* op = ctxo + (size_t)bh*Fc*Dc + f*Dc + half*32;
  #pragma unroll
  for (int j4 = 0; j4 < 8; ++j4) {
    float4 o;
    o.x = acc[j4*4+0]*df; o.y = acc[j4*4+1]*df;
    o.z = acc[j4*4+2]*df; o.w = acc[j4*4+3]*df;
    *(float4*)(op + j4*4) = o;
  }
}

// ---------------- out = Q @ context (VALU) ----------------
__global__ __launch_bounds__(256) void out_kernel(
    const float* __restrict__ AS, const float* __restrict__ ctx,
    float* __restrict__ out) {
  extern __shared__ float smo[];
  float* Asq = smo;            // [64][132]
  float* Cs  = smo + 64*132;   // [128][64]
  int bh = blockIdx.y;
  int row0 = blockIdx.x * 64;
  int tid = threadIdx.x;
  int tr = tid >> 4, tc = tid & 15;
  for (int i = tid; i < 64*32; i += 256) {
    int r = i >> 5, kq = i & 31;
    *(float4*)&Asq[r*132 + kq*4] =
        *(const float4*)(AS + ((size_t)bh*T2c + row0 + r)*Fc + kq*4);
  }
  for (int i = tid; i < 128*16; i += 256) {
    int r = i >> 4, kq = i & 15;
    *(float4*)&Cs[r*64 + kq*4] =
        *(const float4*)(ctx + (size_t)bh*Fc*Dc + r*Dc + kq*4);
  }
  __syncthreads();
  float acc[4][4] = {};
  #pragma unroll 2
  for (int kk = 0; kk < Fc; ++kk) {
    float4 bv = *(const float4*)&Cs[kk*64 + tc*4];
    float a0 = Asq[(tr*4+0)*132 + kk];
    float a1 = Asq[(tr*4+1)*132 + kk];
    float a2 = Asq[(tr*4+2)*132 + kk];
    float a3 = Asq[(tr*4+3)*132 + kk];
    acc[0][0] += a0*bv.x; acc[0][1] += a0*bv.y; acc[0][2] += a0*bv.z; acc[0][3] += a0*bv.w;
    acc[1][0] += a1*bv.x; acc[1][1] += a1*bv.y; acc[1][2] += a1*bv.z; acc[1][3] += a1*bv.w;
    acc[2][0] += a2*bv.x; acc[2][1] += a2*bv.y; acc[2][2] += a2*bv.z; acc[2][3] += a2*bv.w;
    acc[3][0] += a3*bv.x; acc[3][1] += a3*bv.y; acc[3][2] += a3*bv.z; acc[3][3] += a3*bv.w;
  }
  #pragma unroll
  for (int i = 0; i < 4; ++i) {
    float4 o;
    o.x = acc[i][0]; o.y = acc[i][1]; o.z = acc[i][2]; o.w = acc[i][3];
    *(float4*)(out + ((size_t)bh*Nc + row0 + tr*4 + i)*Dc + tc*4) = o;
  }
}

extern "C" void kernel_launch(void* const* d_in, const int* in_sizes, int n_in,
                              void* d_out, int out_size, void* d_ws, size_t ws_size,
                              hipStream_t stream) {
  const float* q    = (const float*)d_in[0];
  const float* k    = (const float*)d_in[1];
  const float* v    = (const float*)d_in[2];
  const float* mask = (const float*)d_in[3];
  const float* sign = (const float*)d_in[4];
  const int*   sketch = (const int*)d_in[5];
  float* out = (float*)d_out;
  float* ws  = (float*)d_ws;

  unsigned short* xsh = (unsigned short*)(ws + OFF_XSH);
  unsigned short* xsm = (unsigned short*)(ws + OFF_XSM);
  unsigned short* xsl = (unsigned short*)(ws + OFF_XSL);
  unsigned short* kh  = (unsigned short*)(ws + OFF_KH);
  unsigned short* km  = (unsigned short*)(ws + OFF_KM);
  unsigned short* kl  = (unsigned short*)(ws + OFF_KL);
  unsigned short* zsc = (unsigned short*)(ws + OFF_ZSC);

  gather_kernel<<<BHc*Jc*16/256, 256, 0, stream>>>(
      q, k, mask, sketch, xsh, xsm, xsl, ws + OFF_DIAG2);
  as_mfma_kernel<<<dim3(T2c/128, BHc), 512, 102912, stream>>>(q, k, mask, xsh, xsm, xsl,
      ws + OFF_DIAG2, sign, ws + OFF_AS);
  stas_kernel<<<BHc, 256, 128*129*sizeof(float), stream>>>(ws + OFF_AS, sketch, sign,
      ws + OFF_STASN, ws + OFF_DINV, kh, km, kl, ws + OFF_GMAX);
  newton_ctx_kernel<<<BHc + 128, 512, 163840, stream>>>(ws + OFF_STASN, kh, km, kl,
      ws + OFF_GMAX, ws + OFF_VBUF, ws + OFF_AS, v, mask, ws + OFF_GPART, zsc);
  ctx_fix_kernel<<<BHc, 256, 0, stream>>>(ws + OFF_GPART, ws + OFF_VBUF,
      ws + OFF_DINV, ws + OFF_CTX);
  out_kernel<<<dim3(Nc/64, BHc), 256, (64*132 + 128*64)*sizeof(float), stream>>>(
      ws + OFF_AS, ws + OFF_CTX, out);
}